// Round 10
// baseline (262.870 us; speedup 1.0000x reference)
//
#include <hip/hip_runtime.h>
#include <hip/hip_fp16.h>

#define NEG_SLOPE 0.2f
#define ALPHA_FLAG 0.05f

typedef _Float16 h2t __attribute__((ext_vector_type(2)));
union h2u { unsigned u; h2t h; __half2 hh; float f; };
static __device__ __forceinline__ h2t u_as_h2(unsigned u) { h2u c; c.u = u; return c.h; }
static __device__ __forceinline__ float h2_as_f(__half2 h) { h2u c; c.hh = h; return c.f; }
static __device__ __forceinline__ h2t f_as_h2(float f) { h2u c; c.f = f; return c.h; }

static inline size_t align256(size_t x) { return (x + 255) & ~(size_t)255; }

// ---------- tiny prep: c = relu(climber@W_c + b_c); gb = c@W_f + b_f ----------
__global__ void prep_kernel(const float* __restrict__ climber,
                            const float* __restrict__ W_c, const float* __restrict__ b_c,
                            const float* __restrict__ W_f1, const float* __restrict__ b_f1,
                            const float* __restrict__ W_f2, const float* __restrict__ b_f2,
                            float* __restrict__ gb1, float* __restrict__ gb2) {
    __shared__ float c_sh[64];
    int g = blockIdx.x, t = threadIdx.x;   // block: 128 threads
    if (t < 64) {
        float acc = b_c[t];
#pragma unroll
        for (int k = 0; k < 4; ++k) acc = fmaf(climber[g * 4 + k], W_c[k * 64 + t], acc);
        c_sh[t] = fmaxf(acc, 0.f);
    }
    __syncthreads();
    float a1 = b_f1[t], a2 = b_f2[t];
#pragma unroll 8
    for (int h = 0; h < 64; ++h) {
        float cv = c_sh[h];
        a1 = fmaf(cv, W_f1[h * 128 + t], a1);
        a2 = fmaf(cv, W_f2[h * 128 + t], a2);
    }
    gb1[g * 128 + t] = a1;
    gb2[g * 128 + t] = a2;
}

// ---------- CSR build (counts zeroed by hipMemsetAsync; self-loop +1 folded into scans) ----------
__global__ void hist_kernel(const int* __restrict__ dst, int E, int* __restrict__ counts) {
    int i4 = (blockIdx.x * blockDim.x + threadIdx.x) * 4;
    if (i4 + 3 < E) {
        int4 d = *(const int4*)&dst[i4];
        atomicAdd(&counts[d.x], 1);
        atomicAdd(&counts[d.y], 1);
        atomicAdd(&counts[d.z], 1);
        atomicAdd(&counts[d.w], 1);
    } else {
        for (int u = 0; u < 4; ++u)
            if (i4 + u < E) atomicAdd(&counts[dst[i4 + u]], 1);
    }
}

#define SCAN_CHUNK 1024
__global__ void scan_partial_kernel(const int* __restrict__ counts, int* __restrict__ block_sums, int N) {
    __shared__ int sh[256];
    int b = blockIdx.x, t = threadIdx.x;
    int idx0 = b * SCAN_CHUNK + t * 4;
    int s = 0;
    if (idx0 + 3 < N) {
        int4 v = *(const int4*)&counts[idx0];
        s = v.x + v.y + v.z + v.w + 4;           // +1 self-loop each
    } else {
#pragma unroll
        for (int u = 0; u < 4; ++u) if (idx0 + u < N) s += counts[idx0 + u] + 1;
    }
    sh[t] = s;
    __syncthreads();
#pragma unroll
    for (int off = 128; off; off >>= 1) {
        if (t < off) sh[t] += sh[t + off];
        __syncthreads();
    }
    if (t == 0) block_sums[b] = sh[0];
}

// final scan: each block re-scans the (<=64) block sums in one wave, then local scan
__global__ void scan_final_kernel(const int* __restrict__ counts, const int* __restrict__ block_sums,
                                  int nb, int* __restrict__ row_ptr, int* __restrict__ fill, int N) {
    __shared__ int sh[256];
    __shared__ int base_sh;
    int b = blockIdx.x, t = threadIdx.x;
    if (t < 64) {
        int v = (t < nb && t < b) ? block_sums[t] : 0;   // masked: sum of blocks before b
#pragma unroll
        for (int off = 32; off; off >>= 1) v += __shfl_xor(v, off);
        if (t == 0) base_sh = v;
    }
    int idx0 = b * SCAN_CHUNK + t * 4;
    int c[4];
    if (idx0 + 3 < N) {
        int4 v = *(const int4*)&counts[idx0];
        c[0] = v.x + 1; c[1] = v.y + 1; c[2] = v.z + 1; c[3] = v.w + 1;
    } else {
#pragma unroll
        for (int u = 0; u < 4; ++u) c[u] = (idx0 + u < N) ? counts[idx0 + u] + 1 : 0;
    }
    int s = c[0] + c[1] + c[2] + c[3];
    sh[t] = s;
    __syncthreads();
#pragma unroll
    for (int off = 1; off < 256; off <<= 1) {
        int add = (t >= off) ? sh[t - off] : 0;
        __syncthreads();
        sh[t] += add;
        __syncthreads();
    }
    int run = base_sh + sh[t] - s;
#pragma unroll
    for (int u = 0; u < 4; ++u) {
        if (idx0 + u < N) {
            row_ptr[idx0 + u] = run;
            fill[idx0 + u] = run;
            run += c[u];
            if (idx0 + u == N - 1) row_ptr[N] = run;
        }
    }
}

__global__ void scatter_kernel(const int* __restrict__ src, const int* __restrict__ dst,
                               int Eh, int N, int* __restrict__ fill, int* __restrict__ csr_src) {
    int t = blockIdx.x * blockDim.x + threadIdx.x;   // Eh = E/2 (E even)
    if (t < Eh) {
        int2 s2 = *(const int2*)&src[t * 2];
        int2 d2 = *(const int2*)&dst[t * 2];
        int p0 = atomicAdd(&fill[d2.x], 1); csr_src[p0] = s2.x;
        int p1 = atomicAdd(&fill[d2.y], 1); csr_src[p1] = s2.y;
    } else {
        int i = t - Eh;
        if (i < N) { int p = atomicAdd(&fill[i], 1); csr_src[p] = i; }   // self-loop
    }
}

// ---------- layer 1: x = FiLM1(x_all@W_in); xh1 = x@W_g1; scores ----------
#define XH_NB 32
__global__ __launch_bounds__(256, 4) void xh1_kernel(
    const float* __restrict__ W_g,
    const float* __restrict__ a_src, const float* __restrict__ a_dst,
    __half* __restrict__ xh, float* __restrict__ s_src, float* __restrict__ s_dst,
    int N,
    const float* __restrict__ x_all, const int* __restrict__ batch,
    const float* __restrict__ W_in, const float* __restrict__ b_in,
    const float* __restrict__ gb1) {
    __shared__ float x_sh[XH_NB * 64];   // 8 KB
    __shared__ float win_sh[6 * 64 + 64];
    int t = threadIdx.x;
    int base = blockIdx.x * XH_NB;
    for (int i = t; i < 448; i += 256)
        win_sh[i] = (i < 384) ? W_in[i] : b_in[i - 384];
    __syncthreads();
    {
        int nd = t >> 3;            // node in tile: 0..31
        int jb = (t & 7) * 8;       // output channel block
        int n = base + nd;
        if (n < N) {
            float4 a = *(const float4*)&x_all[(size_t)n * 8];
            float2 b = *(const float2*)&x_all[(size_t)n * 8 + 4];
            float xa[6] = {a.x, a.y, a.z, a.w, b.x, b.y};
            int g = batch[n];
            const float* gbrow = &gb1[g * 128];
#pragma unroll
            for (int jj = 0; jj < 8; ++jj) {
                int j = jb + jj;
                float acc = win_sh[384 + j];
#pragma unroll
                for (int k = 0; k < 6; ++k) acc = fmaf(xa[k], win_sh[k * 64 + j], acc);
                x_sh[nd * 64 + j] = acc * (1.f + gbrow[j]) + gbrow[64 + j];
            }
        } else {
#pragma unroll
            for (int jj = 0; jj < 8; ++jj) x_sh[nd * 64 + jb + jj] = 0.f;
        }
    }
    __syncthreads();
    int c = t & 63;     // channel within head
    int g = t >> 6;     // wave id: handles nodes g*8..g*8+7, both heads
    float acc0[8], acc1[8];
#pragma unroll
    for (int i = 0; i < 8; ++i) { acc0[i] = 0.f; acc1[i] = 0.f; }
    const float* W0 = W_g + c;
    const float* W1 = W_g + 64 + c;
#pragma unroll 2
    for (int k = 0; k < 64; k += 4) {
        float w0[4], w1[4];
#pragma unroll
        for (int u = 0; u < 4; ++u) { w0[u] = W0[(k + u) * 128]; w1[u] = W1[(k + u) * 128]; }
#pragma unroll
        for (int i = 0; i < 8; ++i) {
            float4 xv = *(const float4*)&x_sh[(g * 8 + i) * 64 + k];
            acc0[i] = fmaf(xv.x, w0[0], acc0[i]);
            acc0[i] = fmaf(xv.y, w0[1], acc0[i]);
            acc0[i] = fmaf(xv.z, w0[2], acc0[i]);
            acc0[i] = fmaf(xv.w, w0[3], acc0[i]);
            acc1[i] = fmaf(xv.x, w1[0], acc1[i]);
            acc1[i] = fmaf(xv.y, w1[1], acc1[i]);
            acc1[i] = fmaf(xv.z, w1[2], acc1[i]);
            acc1[i] = fmaf(xv.w, w1[3], acc1[i]);
        }
    }
    float as0 = a_src[c], ad0 = a_dst[c];
    float as1 = a_src[64 + c], ad1 = a_dst[64 + c];
#pragma unroll
    for (int i = 0; i < 8; ++i) {
        int n = base + g * 8 + i;
        float ps0 = acc0[i] * as0, pd0 = acc0[i] * ad0;
        float ps1 = acc1[i] * as1, pd1 = acc1[i] * ad1;
#pragma unroll
        for (int off = 32; off; off >>= 1) {
            ps0 += __shfl_xor(ps0, off); pd0 += __shfl_xor(pd0, off);
            ps1 += __shfl_xor(ps1, off); pd1 += __shfl_xor(pd1, off);
        }
        if (n < N) {
            if (c == 0) {
                s_src[n * 2 + 0] = ps0; s_src[n * 2 + 1] = ps1;
                s_dst[n * 2 + 0] = pd0; s_dst[n * 2 + 1] = pd1;
            }
            __half2 hv = __floats2half2_rn(acc0[i], acc1[i]);
            *(__half2*)&xh[(size_t)n * 128 + c * 2] = hv;
        }
    }
}

// dot2 helper: acc += w.h0*x.h0 + w.h1*x.h1 (fp32 accumulate)
static __device__ __forceinline__ float dot2acc(unsigned xbits, h2t w, float acc) {
#if __has_builtin(__builtin_amdgcn_fdot2)
    return __builtin_amdgcn_fdot2(u_as_h2(xbits), w, acc, false);
#else
    h2u cx; cx.u = xbits;
    float2 xf = __half22float2(cx.hh);
    h2u cw; cw.h = w;
    float2 wf = __half22float2(cw.hh);
    return fmaf(xf.x, wf.x, fmaf(xf.y, wf.y, acc));
#endif
}

// ---------- shared aggregation core: returns per-lane aggregated value (lane=channel),
// already 0.5*(h0+h1)-combined... no: returns v = mean-over-heads pre-bias value ----------
static __device__ __forceinline__ float agg_core(
    const __half* __restrict__ xh, const float* __restrict__ s_src,
    const float* __restrict__ s_dst, const int* __restrict__ row_ptr,
    const int* __restrict__ csr_src, int n, int N, int lane, int w,
    float2 (* __restrict__ ps_sh)[64], float (* __restrict__ vh_sh)[64]) {
    int beg = 0, end = 0;
    if (n < N) { beg = row_ptr[n]; end = row_ptr[n + 1]; }
    int deg = end - beg;
    float2 sd = (n < N) ? *(const float2*)&s_dst[n * 2] : make_float2(0.f, 0.f);
    const char* xhb = (const char*)xh;
    int sub = lane >> 4;
    unsigned q16 = (unsigned)(lane & 15) * 16u;
    float acc[4] = {0.f, 0.f, 0.f, 0.f};

    if (deg <= 64) {
        float p0 = 0.f, p1 = 0.f; unsigned sb = 0;
        if (lane < deg) {
            int s = csr_src[beg + lane];
            sb = (unsigned)s << 8;
            float2 ss = *(const float2*)&s_src[s * 2];
            float e0 = ss.x + sd.x, e1 = ss.y + sd.y;
            e0 = (e0 > 0.f) ? e0 : NEG_SLOPE * e0;
            e1 = (e1 > 0.f) ? e1 : NEG_SLOPE * e1;
            p0 = __expf(e0); p1 = __expf(e1);
        }
        float dp0 = p0, dp1 = p1;
#pragma unroll
        for (int off = 32; off; off >>= 1) {
            dp0 += __shfl_xor(dp0, off);
            dp1 += __shfl_xor(dp1, off);
        }
        float i0 = 0.5f / (dp0 + 1e-16f), i1 = 0.5f / (dp1 + 1e-16f);
        ps_sh[w][lane] = make_float2(h2_as_f(__floats2half2_rn(p0 * i0, p1 * i1)),
                                     __uint_as_float(sb));
        int mr = (deg + 3) & ~3;
        for (int j = 0; j < mr; j += 4) {
            float2 ps = ps_sh[w][j + sub];                   // broadcast x4
            h2t wpk = f_as_h2(ps.x);
            unsigned voff = __float_as_uint(ps.y) + q16;
            uint4 hv = *(const uint4*)(xhb + voff);          // 4 x half2
            acc[0] = dot2acc(hv.x, wpk, acc[0]);
            acc[1] = dot2acc(hv.y, wpk, acc[1]);
            acc[2] = dot2acc(hv.z, wpk, acc[2]);
            acc[3] = dot2acc(hv.w, wpk, acc[3]);
        }
    } else {
        float dp0 = 0.f, dp1 = 0.f;
        for (int chunk = beg; chunk < end; chunk += 64) {
            int m = end - chunk; if (m > 64) m = 64;
            if (lane < m) {
                int s = csr_src[chunk + lane];
                float2 ss = *(const float2*)&s_src[s * 2];
                float e0 = ss.x + sd.x, e1 = ss.y + sd.y;
                e0 = (e0 > 0.f) ? e0 : NEG_SLOPE * e0;
                e1 = (e1 > 0.f) ? e1 : NEG_SLOPE * e1;
                dp0 += __expf(e0); dp1 += __expf(e1);
            }
        }
#pragma unroll
        for (int off = 32; off; off >>= 1) {
            dp0 += __shfl_xor(dp0, off);
            dp1 += __shfl_xor(dp1, off);
        }
        float i0 = 0.5f / (dp0 + 1e-16f), i1 = 0.5f / (dp1 + 1e-16f);
        for (int chunk = beg; chunk < end; chunk += 64) {
            int m = end - chunk; if (m > 64) m = 64;
            float p0 = 0.f, p1 = 0.f; unsigned sb = 0;
            if (lane < m) {
                int s = csr_src[chunk + lane];
                sb = (unsigned)s << 8;
                float2 ss = *(const float2*)&s_src[s * 2];
                float e0 = ss.x + sd.x, e1 = ss.y + sd.y;
                e0 = (e0 > 0.f) ? e0 : NEG_SLOPE * e0;
                e1 = (e1 > 0.f) ? e1 : NEG_SLOPE * e1;
                p0 = __expf(e0); p1 = __expf(e1);
            }
            ps_sh[w][lane] = make_float2(h2_as_f(__floats2half2_rn(p0 * i0, p1 * i1)),
                                         __uint_as_float(sb));
            int mr = (m + 3) & ~3;
            for (int j = 0; j < mr; j += 4) {
                float2 ps = ps_sh[w][j + sub];
                h2t wpk = f_as_h2(ps.x);
                unsigned voff = __float_as_uint(ps.y) + q16;
                uint4 hv = *(const uint4*)(xhb + voff);
                acc[0] = dot2acc(hv.x, wpk, acc[0]);
                acc[1] = dot2acc(hv.y, wpk, acc[1]);
                acc[2] = dot2acc(hv.z, wpk, acc[2]);
                acc[3] = dot2acc(hv.w, wpk, acc[3]);
            }
        }
    }
#pragma unroll
    for (int u = 0; u < 4; ++u) {
        acc[u] += __shfl_xor(acc[u], 16);
        acc[u] += __shfl_xor(acc[u], 32);
    }
    if (lane < 16) *(float4*)&vh_sh[w][lane * 4] = make_float4(acc[0], acc[1], acc[2], acc[3]);
    return vh_sh[w][lane];   // wave-coherent
}

// ---------- layer-1 aggregation fused with FiLM2 + xh2 GEMM + layer-2 scores ----------
// Block = 4 waves = 4 nodes. After per-wave aggregation, one barrier, then threads
// remap to (pair = w>>1, head = w&1, c = lane): each computes xh2[c,h] for 2 nodes
// (W column loads amortized x2), shuffle-reduces a_src2/a_dst2 scores, stages rows
// in LDS, block-wide coalesced writeout.
__global__ __launch_bounds__(256) void agg_film_xh_kernel(
    const __half* __restrict__ xh1, const float* __restrict__ s_src1,
    const float* __restrict__ s_dst1, const int* __restrict__ row_ptr,
    const int* __restrict__ csr_src, const float* __restrict__ b_g1,
    const int* __restrict__ batch, const float* __restrict__ gb2,
    const float* __restrict__ W_g2, const float* __restrict__ a_src2,
    const float* __restrict__ a_dst2,
    __half* __restrict__ xh2, float* __restrict__ s_src2, float* __restrict__ s_dst2,
    int N) {
    __shared__ float2 ps_sh[4][64];
    __shared__ float v_sh[4][64];
    __shared__ __half xh_sh[4][128];
    int t = threadIdx.x;
    int lane = t & 63;
    int w = t >> 6;
    int node0 = blockIdx.x * 4;
    int n = node0 + w;
    float v = agg_core(xh1, s_src1, s_dst1, row_ptr, csr_src, n, N, lane, w, ps_sh, v_sh);
    v = fmaxf(v + b_g1[lane], 0.f);
    if (n < N) {
        int g = batch[n];
        v = v * (1.f + gb2[g * 128 + lane]) + gb2[g * 128 + 64 + lane];
    }
    v_sh[w][lane] = v;
    __syncthreads();
    // remap: pair pr (nodes node0+2pr, node0+2pr+1), head h, channel c
    int c = lane;
    int h = w & 1;
    int pr = w >> 1;
    const float* Wc = W_g2 + h * 64 + c;
    const float* vA = v_sh[2 * pr];
    const float* vB = v_sh[2 * pr + 1];
    float accA = 0.f, accB = 0.f;
#pragma unroll 4
    for (int k = 0; k < 64; k += 4) {
        float w0 = Wc[(k + 0) * 128], w1 = Wc[(k + 1) * 128];
        float w2 = Wc[(k + 2) * 128], w3 = Wc[(k + 3) * 128];
        float4 a4 = *(const float4*)&vA[k];
        float4 b4 = *(const float4*)&vB[k];
        accA = fmaf(a4.x, w0, accA); accB = fmaf(b4.x, w0, accB);
        accA = fmaf(a4.y, w1, accA); accB = fmaf(b4.y, w1, accB);
        accA = fmaf(a4.z, w2, accA); accB = fmaf(b4.z, w2, accB);
        accA = fmaf(a4.w, w3, accA); accB = fmaf(b4.w, w3, accB);
    }
    float as = a_src2[h * 64 + c], ad = a_dst2[h * 64 + c];
    float psA = accA * as, pdA = accA * ad;
    float psB = accB * as, pdB = accB * ad;
#pragma unroll
    for (int off = 32; off; off >>= 1) {
        psA += __shfl_xor(psA, off); pdA += __shfl_xor(pdA, off);
        psB += __shfl_xor(psB, off); pdB += __shfl_xor(pdB, off);
    }
    int nA = node0 + 2 * pr, nB = nA + 1;
    if (lane == 0) {
        if (nA < N) { s_src2[nA * 2 + h] = psA; s_dst2[nA * 2 + h] = pdA; }
        if (nB < N) { s_src2[nB * 2 + h] = psB; s_dst2[nB * 2 + h] = pdB; }
    }
    xh_sh[2 * pr][c * 2 + h] = __float2half(accA);
    xh_sh[2 * pr + 1][c * 2 + h] = __float2half(accB);
    __syncthreads();
    int nw = node0 + (t >> 6);
    if (nw < N) {
        unsigned val = ((const unsigned*)xh_sh)[t];
        *(unsigned*)((char*)xh2 + (size_t)nw * 256 + (t & 63) * 4) = val;
    }
}

// ---------- layer-2 aggregation fused with classifier + flag head ----------
__global__ __launch_bounds__(256) void agg_cls_kernel(
    const __half* __restrict__ xh, const float* __restrict__ s_src,
    const float* __restrict__ s_dst, const int* __restrict__ row_ptr,
    const int* __restrict__ csr_src, const float* __restrict__ b_g, int N,
    const float* __restrict__ x_all,
    const float* __restrict__ W_cl1, const float* __restrict__ b_cl1,
    const float* __restrict__ W_cl2, const float* __restrict__ b_cl2,
    const float* __restrict__ W_fh1, const float* __restrict__ b_fh1,
    const float* __restrict__ W_fh2, const float* __restrict__ b_fh2,
    float* __restrict__ out) {
    __shared__ float2 ps_sh[4][64];
    __shared__ float vh_sh[4][64];
    int lane = threadIdx.x & 63;
    int w = threadIdx.x >> 6;
    int n = (blockIdx.x * blockDim.x + threadIdx.x) >> 6;
    if (n >= N) return;
    float v = agg_core(xh, s_src, s_dst, row_ptr, csr_src, n, N, lane, w, ps_sh, vh_sh);
    v = fmaxf(v + b_g[lane], 0.f);
    vh_sh[w][lane] = v;   // wave-coherent
    float h = b_cl1[lane];
#pragma unroll 4
    for (int k = 0; k < 64; k += 4) {
        float4 vq = *(const float4*)&vh_sh[w][k];
        h = fmaf(vq.x, W_cl1[(k + 0) * 64 + lane], h);
        h = fmaf(vq.y, W_cl1[(k + 1) * 64 + lane], h);
        h = fmaf(vq.z, W_cl1[(k + 2) * 64 + lane], h);
        h = fmaf(vq.w, W_cl1[(k + 3) * 64 + lane], h);
    }
    h = fmaxf(h, 0.f);
    float4 w2 = *(const float4*)&W_cl2[lane * 4];
    float o0 = h * w2.x, o1 = h * w2.y, o2 = h * w2.z, o3 = h * w2.w;
#pragma unroll
    for (int off = 32; off; off >>= 1) {
        o0 += __shfl_xor(o0, off); o1 += __shfl_xor(o1, off);
        o2 += __shfl_xor(o2, off); o3 += __shfl_xor(o3, off);
    }
    if (lane < 4) {
        float f0 = x_all[(size_t)n * 8 + 6], f1 = x_all[(size_t)n * 8 + 7];
        float lf = b_fh2[lane];
#pragma unroll
        for (int m = 0; m < 8; ++m) {
            float fm = fmaxf(fmaf(f0, W_fh1[m], fmaf(f1, W_fh1[8 + m], b_fh1[m])), 0.f);
            lf = fmaf(fm, W_fh2[m * 4 + lane], lf);
        }
        float om = (lane == 0) ? o0 : (lane == 1) ? o1 : (lane == 2) ? o2 : o3;
        out[(size_t)n * 4 + lane] = om + b_cl2[lane] + ALPHA_FLAG * lf;
    }
}

extern "C" void kernel_launch(void* const* d_in, const int* in_sizes, int n_in,
                              void* d_out, int out_size, void* d_ws, size_t ws_size,
                              hipStream_t stream) {
    const float* x_all   = (const float*)d_in[0];
    const float* climber = (const float*)d_in[1];
    const int*   eidx    = (const int*)d_in[2];
    const int*   batch   = (const int*)d_in[3];
    const float* W_in  = (const float*)d_in[4];
    const float* b_in  = (const float*)d_in[5];
    const float* W_c   = (const float*)d_in[6];
    const float* b_c   = (const float*)d_in[7];
    const float* W_f1  = (const float*)d_in[8];
    const float* b_f1  = (const float*)d_in[9];
    const float* W_f2  = (const float*)d_in[10];
    const float* b_f2  = (const float*)d_in[11];
    const float* W_g1  = (const float*)d_in[12];
    const float* a_s1  = (const float*)d_in[13];
    const float* a_d1  = (const float*)d_in[14];
    const float* b_g1  = (const float*)d_in[15];
    const float* W_g2  = (const float*)d_in[16];
    const float* a_s2  = (const float*)d_in[17];
    const float* a_d2  = (const float*)d_in[18];
    const float* b_g2  = (const float*)d_in[19];
    const float* W_cl1 = (const float*)d_in[20];
    const float* b_cl1 = (const float*)d_in[21];
    const float* W_cl2 = (const float*)d_in[22];
    const float* b_cl2 = (const float*)d_in[23];
    const float* W_fh1 = (const float*)d_in[24];
    const float* b_fh1 = (const float*)d_in[25];
    const float* W_fh2 = (const float*)d_in[26];
    const float* b_fh2 = (const float*)d_in[27];
    float* out = (float*)d_out;

    const int N = in_sizes[0] / 8;      // 50000
    const int E = in_sizes[2] / 2;      // 800000 (even)
    const int G = in_sizes[1] / 4;      // 128
    const int* src = eidx;
    const int* dst = eidx + E;
    const int NB_SCAN = (N + SCAN_CHUNK - 1) / SCAN_CHUNK;   // 49 (<= 64)

    char* ws = (char*)d_ws;
    size_t off = 0;
    auto alloc = [&](size_t bytes) { char* p = ws + off; off += align256(bytes); return p; };
    float*  gb1     = (float*)alloc((size_t)G * 128 * 4);
    float*  gb2     = (float*)alloc((size_t)G * 128 * 4);
    __half* xh1     = (__half*)alloc((size_t)N * 128 * 2);
    __half* xh2     = (__half*)alloc((size_t)N * 128 * 2);
    float*  s_src1  = (float*)alloc((size_t)N * 2 * 4);
    float*  s_dst1  = (float*)alloc((size_t)N * 2 * 4);
    float*  s_src2  = (float*)alloc((size_t)N * 2 * 4);
    float*  s_dst2  = (float*)alloc((size_t)N * 2 * 4);
    int*    counts  = (int*)alloc((size_t)N * 4);
    int*    fill    = (int*)alloc((size_t)N * 4);
    int*    row_ptr = (int*)alloc((size_t)(N + 1) * 4);
    int*    csr_src = (int*)alloc((size_t)(E + N) * 4);
    int*    bsums   = (int*)alloc((size_t)64 * 4);
    (void)ws_size;

    // 1. FiLM params
    prep_kernel<<<G, 128, 0, stream>>>(climber, W_c, b_c, W_f1, b_f1, W_f2, b_f2, gb1, gb2);
    // 2. CSR build (shared by both layers)
    hipMemsetAsync(counts, 0, (size_t)N * 4, stream);
    hist_kernel<<<(E / 4 + 255) / 256, 256, 0, stream>>>(dst, E, counts);
    scan_partial_kernel<<<NB_SCAN, 256, 0, stream>>>(counts, bsums, N);
    scan_final_kernel<<<NB_SCAN, 256, 0, stream>>>(counts, bsums, NB_SCAN, row_ptr, fill, N);
    scatter_kernel<<<(E / 2 + N + 255) / 256, 256, 0, stream>>>(src, dst, E / 2, N, fill, csr_src);
    // 3. layer 1 transform (input MLP + FiLM1 + W_g1 + scores)
    xh1_kernel<<<(N + XH_NB - 1) / XH_NB, 256, 0, stream>>>(W_g1, a_s1, a_d1, xh1,
                                                            s_src1, s_dst1, N,
                                                            x_all, batch, W_in, b_in, gb1);
    // 4. layer-1 aggregation + FiLM2 + xh2 GEMM + layer-2 scores (fused)
    agg_film_xh_kernel<<<(N + 3) / 4, 256, 0, stream>>>(xh1, s_src1, s_dst1, row_ptr, csr_src,
                                                        b_g1, batch, gb2, W_g2, a_s2, a_d2,
                                                        xh2, s_src2, s_dst2, N);
    // 5. layer-2 aggregation + classifier + flag head (fused)
    agg_cls_kernel<<<(N * 64 + 255) / 256, 256, 0, stream>>>(xh2, s_src2, s_dst2, row_ptr, csr_src,
                                                             b_g2, N, x_all, W_cl1, b_cl1,
                                                             W_cl2, b_cl2, W_fh1, b_fh1,
                                                             W_fh2, b_fh2, out);
}

// Round 11
// 228.623 us; speedup vs baseline: 1.1498x; 1.1498x over previous
//
#include <hip/hip_runtime.h>
#include <hip/hip_fp16.h>

#define NEG_SLOPE 0.2f
#define ALPHA_FLAG 0.05f

typedef _Float16 h2t __attribute__((ext_vector_type(2)));
union h2u { unsigned u; h2t h; __half2 hh; float f; };
static __device__ __forceinline__ h2t u_as_h2(unsigned u) { h2u c; c.u = u; return c.h; }
static __device__ __forceinline__ float h2_as_f(__half2 h) { h2u c; c.hh = h; return c.f; }
static __device__ __forceinline__ h2t f_as_h2(float f) { h2u c; c.f = f; return c.h; }

static inline size_t align256(size_t x) { return (x + 255) & ~(size_t)255; }

// ---------- tiny prep: c = relu(climber@W_c + b_c); gb = c@W_f + b_f ----------
__global__ void prep_kernel(const float* __restrict__ climber,
                            const float* __restrict__ W_c, const float* __restrict__ b_c,
                            const float* __restrict__ W_f1, const float* __restrict__ b_f1,
                            const float* __restrict__ W_f2, const float* __restrict__ b_f2,
                            float* __restrict__ gb1, float* __restrict__ gb2) {
    __shared__ float c_sh[64];
    int g = blockIdx.x, t = threadIdx.x;   // block: 128 threads
    if (t < 64) {
        float acc = b_c[t];
#pragma unroll
        for (int k = 0; k < 4; ++k) acc = fmaf(climber[g * 4 + k], W_c[k * 64 + t], acc);
        c_sh[t] = fmaxf(acc, 0.f);
    }
    __syncthreads();
    float a1 = b_f1[t], a2 = b_f2[t];
#pragma unroll 8
    for (int h = 0; h < 64; ++h) {
        float cv = c_sh[h];
        a1 = fmaf(cv, W_f1[h * 128 + t], a1);
        a2 = fmaf(cv, W_f2[h * 128 + t], a2);
    }
    gb1[g * 128 + t] = a1;
    gb2[g * 128 + t] = a2;
}

// ---------- CSR build ----------
// counts zeroed by hipMemsetAsync. hist also records each edge's within-row rank
// (the atomicAdd return), making the scatter pass atomic-free.
__global__ void hist_kernel(const int* __restrict__ dst, int E,
                            int* __restrict__ counts, int* __restrict__ ranks) {
    int i4 = (blockIdx.x * blockDim.x + threadIdx.x) * 4;
    if (i4 + 3 < E) {
        int4 d = *(const int4*)&dst[i4];
        int4 r;
        r.x = atomicAdd(&counts[d.x], 1);
        r.y = atomicAdd(&counts[d.y], 1);
        r.z = atomicAdd(&counts[d.z], 1);
        r.w = atomicAdd(&counts[d.w], 1);
        *(int4*)&ranks[i4] = r;
    } else {
        for (int u = 0; u < 4; ++u)
            if (i4 + u < E) ranks[i4 + u] = atomicAdd(&counts[dst[i4 + u]], 1);
    }
}

// single-pass scan: block b computes its own prefix (sum of preceding full chunks),
// then local chunk scan. Self-loop +1 per node folded in. Writes row_ptr only.
#define SCAN_CHUNK 1024
__global__ void scan_kernel(const int* __restrict__ counts, int* __restrict__ row_ptr, int N) {
    __shared__ int sh[256];
    int b = blockIdx.x, t = threadIdx.x;
    // prefix over preceding chunks (all full: b*1024 <= N for every non-last block boundary)
    int pre = 0;
    for (int i0 = t * 4; i0 < b * SCAN_CHUNK; i0 += 1024) {
        int4 v = *(const int4*)&counts[i0];
        pre += v.x + v.y + v.z + v.w + 4;   // +1 self-loop each
    }
    sh[t] = pre;
    __syncthreads();
#pragma unroll
    for (int off = 128; off; off >>= 1) {
        if (t < off) sh[t] += sh[t + off];
        __syncthreads();
    }
    int base = sh[0];
    __syncthreads();
    // local chunk scan
    int idx0 = b * SCAN_CHUNK + t * 4;
    int c[4];
    if (idx0 + 3 < N) {
        int4 v = *(const int4*)&counts[idx0];
        c[0] = v.x + 1; c[1] = v.y + 1; c[2] = v.z + 1; c[3] = v.w + 1;
    } else {
#pragma unroll
        for (int u = 0; u < 4; ++u) c[u] = (idx0 + u < N) ? counts[idx0 + u] + 1 : 0;
    }
    int s = c[0] + c[1] + c[2] + c[3];
    sh[t] = s;
    __syncthreads();
#pragma unroll
    for (int off = 1; off < 256; off <<= 1) {
        int add = (t >= off) ? sh[t - off] : 0;
        __syncthreads();
        sh[t] += add;
        __syncthreads();
    }
    int run = base + sh[t] - s;
#pragma unroll
    for (int u = 0; u < 4; ++u) {
        if (idx0 + u < N) {
            row_ptr[idx0 + u] = run;
            run += c[u];
            if (idx0 + u == N - 1) row_ptr[N] = run;
        }
    }
}

// atomic-free scatter: pos = row_ptr[dst] + rank; self-loop at row_ptr[n] + counts[n]
__global__ void scatter_kernel(const int* __restrict__ src, const int* __restrict__ dst,
                               const int* __restrict__ ranks, const int* __restrict__ counts,
                               const int* __restrict__ row_ptr,
                               int Eh, int N, int* __restrict__ csr_src) {
    int t = blockIdx.x * blockDim.x + threadIdx.x;   // Eh = E/2 (E even)
    if (t < Eh) {
        int2 s2 = *(const int2*)&src[t * 2];
        int2 d2 = *(const int2*)&dst[t * 2];
        int2 r2 = *(const int2*)&ranks[t * 2];
        csr_src[row_ptr[d2.x] + r2.x] = s2.x;
        csr_src[row_ptr[d2.y] + r2.y] = s2.y;
    } else {
        int i = t - Eh;
        if (i < N) csr_src[row_ptr[i] + counts[i]] = i;   // self-loop (last slot)
    }
}

// ---------- per-layer: xh = x@W_g (fp16 out, [n][c][h] interleaved); scores ----------
// in_mode=1: compute x on the fly from x_all (input transform + FiLM1), layer 1
// in_mode=0: load x (fp16) from xbuf (layer 2)
#define XH_NB 32
__global__ __launch_bounds__(256, 4) void xh_kernel(
    const __half* __restrict__ xhalf, const float* __restrict__ W_g,
    const float* __restrict__ a_src, const float* __restrict__ a_dst,
    __half* __restrict__ xh, float* __restrict__ s_src, float* __restrict__ s_dst,
    int N, int in_mode,
    const float* __restrict__ x_all, const int* __restrict__ batch,
    const float* __restrict__ W_in, const float* __restrict__ b_in,
    const float* __restrict__ gb1) {
    __shared__ float x_sh[XH_NB * 64];   // 8 KB
    __shared__ float win_sh[6 * 64 + 64];
    int t = threadIdx.x;
    int base = blockIdx.x * XH_NB;
    if (in_mode) {
        for (int i = t; i < 448; i += 256)
            win_sh[i] = (i < 384) ? W_in[i] : b_in[i - 384];
        __syncthreads();
        int nd = t >> 3;            // node in tile: 0..31
        int jb = (t & 7) * 8;       // output channel block
        int n = base + nd;
        if (n < N) {
            float4 a = *(const float4*)&x_all[(size_t)n * 8];
            float2 b = *(const float2*)&x_all[(size_t)n * 8 + 4];
            float xa[6] = {a.x, a.y, a.z, a.w, b.x, b.y};
            int g = batch[n];
            const float* gbrow = &gb1[g * 128];
#pragma unroll
            for (int jj = 0; jj < 8; ++jj) {
                int j = jb + jj;
                float acc = win_sh[384 + j];
#pragma unroll
                for (int k = 0; k < 6; ++k) acc = fmaf(xa[k], win_sh[k * 64 + j], acc);
                x_sh[nd * 64 + j] = acc * (1.f + gbrow[j]) + gbrow[64 + j];
            }
        } else {
#pragma unroll
            for (int jj = 0; jj < 8; ++jj) x_sh[nd * 64 + jb + jj] = 0.f;
        }
    } else {
        int nvalid = N - base; if (nvalid > XH_NB) nvalid = XH_NB;
        int nhalves = nvalid * 64;   // multiple of 64; t*8 either fully in or out
        int idx = t * 8;
        uint4 raw = make_uint4(0, 0, 0, 0);
        if (idx < nhalves) raw = *(const uint4*)&xhalf[(size_t)base * 64 + idx];
        float2 f0 = __half22float2(*(__half2*)&raw.x);
        float2 f1 = __half22float2(*(__half2*)&raw.y);
        float2 f2 = __half22float2(*(__half2*)&raw.z);
        float2 f3 = __half22float2(*(__half2*)&raw.w);
        x_sh[idx + 0] = f0.x; x_sh[idx + 1] = f0.y;
        x_sh[idx + 2] = f1.x; x_sh[idx + 3] = f1.y;
        x_sh[idx + 4] = f2.x; x_sh[idx + 5] = f2.y;
        x_sh[idx + 6] = f3.x; x_sh[idx + 7] = f3.y;
    }
    __syncthreads();
    int c = t & 63;     // channel within head
    int g = t >> 6;     // wave id: handles nodes g*8..g*8+7, both heads
    float acc0[8], acc1[8];
#pragma unroll
    for (int i = 0; i < 8; ++i) { acc0[i] = 0.f; acc1[i] = 0.f; }
    const float* W0 = W_g + c;
    const float* W1 = W_g + 64 + c;
#pragma unroll 2
    for (int k = 0; k < 64; k += 4) {
        float w0[4], w1[4];
#pragma unroll
        for (int u = 0; u < 4; ++u) { w0[u] = W0[(k + u) * 128]; w1[u] = W1[(k + u) * 128]; }
#pragma unroll
        for (int i = 0; i < 8; ++i) {
            float4 xv = *(const float4*)&x_sh[(g * 8 + i) * 64 + k];
            acc0[i] = fmaf(xv.x, w0[0], acc0[i]);
            acc0[i] = fmaf(xv.y, w0[1], acc0[i]);
            acc0[i] = fmaf(xv.z, w0[2], acc0[i]);
            acc0[i] = fmaf(xv.w, w0[3], acc0[i]);
            acc1[i] = fmaf(xv.x, w1[0], acc1[i]);
            acc1[i] = fmaf(xv.y, w1[1], acc1[i]);
            acc1[i] = fmaf(xv.z, w1[2], acc1[i]);
            acc1[i] = fmaf(xv.w, w1[3], acc1[i]);
        }
    }
    float as0 = a_src[c], ad0 = a_dst[c];
    float as1 = a_src[64 + c], ad1 = a_dst[64 + c];
#pragma unroll
    for (int i = 0; i < 8; ++i) {
        int n = base + g * 8 + i;
        float ps0 = acc0[i] * as0, pd0 = acc0[i] * ad0;
        float ps1 = acc1[i] * as1, pd1 = acc1[i] * ad1;
#pragma unroll
        for (int off = 32; off; off >>= 1) {
            ps0 += __shfl_xor(ps0, off); pd0 += __shfl_xor(pd0, off);
            ps1 += __shfl_xor(ps1, off); pd1 += __shfl_xor(pd1, off);
        }
        if (n < N) {
            if (c == 0) {
                s_src[n * 2 + 0] = ps0; s_src[n * 2 + 1] = ps1;
                s_dst[n * 2 + 0] = pd0; s_dst[n * 2 + 1] = pd1;
            }
            __half2 hv = __floats2half2_rn(acc0[i], acc1[i]);
            *(__half2*)&xh[(size_t)n * 128 + c * 2] = hv;
        }
    }
}

// dot2 helper: acc += w.h0*x.h0 + w.h1*x.h1 (fp32 accumulate)
static __device__ __forceinline__ float dot2acc(unsigned xbits, h2t w, float acc) {
#if __has_builtin(__builtin_amdgcn_fdot2)
    return __builtin_amdgcn_fdot2(u_as_h2(xbits), w, acc, false);
#else
    h2u cx; cx.u = xbits;
    float2 xf = __half22float2(cx.hh);
    h2u cw; cw.h = w;
    float2 wf = __half22float2(cw.hh);
    return fmaf(xf.x, wf.x, fmaf(xf.y, wf.y, acc));
#endif
}

// ---------- wave-per-node aggregation core (dot2, pre-normalized softmax) ----------
template <int MODE>
static __device__ __forceinline__ void agg_impl(
    const __half* __restrict__ xh, const float* __restrict__ s_src,
    const float* __restrict__ s_dst, const int* __restrict__ row_ptr,
    const int* __restrict__ csr_src, const float* __restrict__ b_g,
    const int* __restrict__ batch, const float* __restrict__ gb_film,
    __half* __restrict__ xout_h, int N,
    const float* __restrict__ x_all,
    const float* __restrict__ W_cl1, const float* __restrict__ b_cl1,
    const float* __restrict__ W_cl2, const float* __restrict__ b_cl2,
    const float* __restrict__ W_fh1, const float* __restrict__ b_fh1,
    const float* __restrict__ W_fh2, const float* __restrict__ b_fh2,
    float* __restrict__ out) {
    __shared__ float2 ps_sh[4][64];   // (packed half2 alpha, row byte-offset)
    __shared__ float vh_sh[4][64];
    int lane = threadIdx.x & 63;
    int w = threadIdx.x >> 6;
    int n = (blockIdx.x * blockDim.x + threadIdx.x) >> 6;
    if (n >= N) return;
    int beg = row_ptr[n], end = row_ptr[n + 1];
    int deg = end - beg;
    float2 sd = *(const float2*)&s_dst[n * 2];
    const char* xhb = (const char*)xh;
    int sub = lane >> 4;
    unsigned q16 = (unsigned)(lane & 15) * 16u;
    float acc[4] = {0.f, 0.f, 0.f, 0.f};

    if (deg <= 64) {
        float p0 = 0.f, p1 = 0.f; unsigned sb = 0;
        if (lane < deg) {
            int s = csr_src[beg + lane];
            sb = (unsigned)s << 8;
            float2 ss = *(const float2*)&s_src[s * 2];
            float e0 = ss.x + sd.x, e1 = ss.y + sd.y;
            e0 = (e0 > 0.f) ? e0 : NEG_SLOPE * e0;
            e1 = (e1 > 0.f) ? e1 : NEG_SLOPE * e1;
            p0 = __expf(e0); p1 = __expf(e1);
        }
        float dp0 = p0, dp1 = p1;
#pragma unroll
        for (int off = 32; off; off >>= 1) {
            dp0 += __shfl_xor(dp0, off);
            dp1 += __shfl_xor(dp1, off);
        }
        float i0 = 0.5f / (dp0 + 1e-16f), i1 = 0.5f / (dp1 + 1e-16f);
        ps_sh[w][lane] = make_float2(h2_as_f(__floats2half2_rn(p0 * i0, p1 * i1)),
                                     __uint_as_float(sb));
        int mr = (deg + 3) & ~3;
        for (int j = 0; j < mr; j += 4) {
            float2 ps = ps_sh[w][j + sub];                   // broadcast x4
            h2t wpk = f_as_h2(ps.x);
            unsigned voff = __float_as_uint(ps.y) + q16;
            uint4 hv = *(const uint4*)(xhb + voff);          // 4 x half2
            acc[0] = dot2acc(hv.x, wpk, acc[0]);
            acc[1] = dot2acc(hv.y, wpk, acc[1]);
            acc[2] = dot2acc(hv.z, wpk, acc[2]);
            acc[3] = dot2acc(hv.w, wpk, acc[3]);
        }
    } else {
        float dp0 = 0.f, dp1 = 0.f;
        for (int chunk = beg; chunk < end; chunk += 64) {
            int m = end - chunk; if (m > 64) m = 64;
            if (lane < m) {
                int s = csr_src[chunk + lane];
                float2 ss = *(const float2*)&s_src[s * 2];
                float e0 = ss.x + sd.x, e1 = ss.y + sd.y;
                e0 = (e0 > 0.f) ? e0 : NEG_SLOPE * e0;
                e1 = (e1 > 0.f) ? e1 : NEG_SLOPE * e1;
                dp0 += __expf(e0); dp1 += __expf(e1);
            }
        }
#pragma unroll
        for (int off = 32; off; off >>= 1) {
            dp0 += __shfl_xor(dp0, off);
            dp1 += __shfl_xor(dp1, off);
        }
        float i0 = 0.5f / (dp0 + 1e-16f), i1 = 0.5f / (dp1 + 1e-16f);
        for (int chunk = beg; chunk < end; chunk += 64) {
            int m = end - chunk; if (m > 64) m = 64;
            float p0 = 0.f, p1 = 0.f; unsigned sb = 0;
            if (lane < m) {
                int s = csr_src[chunk + lane];
                sb = (unsigned)s << 8;
                float2 ss = *(const float2*)&s_src[s * 2];
                float e0 = ss.x + sd.x, e1 = ss.y + sd.y;
                e0 = (e0 > 0.f) ? e0 : NEG_SLOPE * e0;
                e1 = (e1 > 0.f) ? e1 : NEG_SLOPE * e1;
                p0 = __expf(e0); p1 = __expf(e1);
            }
            ps_sh[w][lane] = make_float2(h2_as_f(__floats2half2_rn(p0 * i0, p1 * i1)),
                                         __uint_as_float(sb));
            int mr = (m + 3) & ~3;
            for (int j = 0; j < mr; j += 4) {
                float2 ps = ps_sh[w][j + sub];
                h2t wpk = f_as_h2(ps.x);
                unsigned voff = __float_as_uint(ps.y) + q16;
                uint4 hv = *(const uint4*)(xhb + voff);
                acc[0] = dot2acc(hv.x, wpk, acc[0]);
                acc[1] = dot2acc(hv.y, wpk, acc[1]);
                acc[2] = dot2acc(hv.z, wpk, acc[2]);
                acc[3] = dot2acc(hv.w, wpk, acc[3]);
            }
        }
    }
#pragma unroll
    for (int u = 0; u < 4; ++u) {
        acc[u] += __shfl_xor(acc[u], 16);
        acc[u] += __shfl_xor(acc[u], 32);
    }
    if (lane < 16) *(float4*)&vh_sh[w][lane * 4] = make_float4(acc[0], acc[1], acc[2], acc[3]);
    float v = vh_sh[w][lane] + b_g[lane];
    v = fmaxf(v, 0.f);
    if (MODE == 0) {
        int g = batch[n];
        v = v * (1.f + gb_film[g * 128 + lane]) + gb_film[g * 128 + 64 + lane];
        xout_h[(size_t)n * 64 + lane] = __float2half(v);
        return;
    }
    // ---- fused classifier ----
    vh_sh[w][lane] = v;
    float h = b_cl1[lane];
#pragma unroll 4
    for (int k = 0; k < 64; k += 4) {
        float4 vq = *(const float4*)&vh_sh[w][k];
        h = fmaf(vq.x, W_cl1[(k + 0) * 64 + lane], h);
        h = fmaf(vq.y, W_cl1[(k + 1) * 64 + lane], h);
        h = fmaf(vq.z, W_cl1[(k + 2) * 64 + lane], h);
        h = fmaf(vq.w, W_cl1[(k + 3) * 64 + lane], h);
    }
    h = fmaxf(h, 0.f);
    float4 w2 = *(const float4*)&W_cl2[lane * 4];
    float o0 = h * w2.x, o1 = h * w2.y, o2 = h * w2.z, o3 = h * w2.w;
#pragma unroll
    for (int off = 32; off; off >>= 1) {
        o0 += __shfl_xor(o0, off); o1 += __shfl_xor(o1, off);
        o2 += __shfl_xor(o2, off); o3 += __shfl_xor(o3, off);
    }
    if (lane < 4) {
        float f0 = x_all[(size_t)n * 8 + 6], f1 = x_all[(size_t)n * 8 + 7];
        float lf = b_fh2[lane];
#pragma unroll
        for (int m = 0; m < 8; ++m) {
            float fm = fmaxf(fmaf(f0, W_fh1[m], fmaf(f1, W_fh1[8 + m], b_fh1[m])), 0.f);
            lf = fmaf(fm, W_fh2[m * 4 + lane], lf);
        }
        float om = (lane == 0) ? o0 : (lane == 1) ? o1 : (lane == 2) ? o2 : o3;
        out[(size_t)n * 4 + lane] = om + b_cl2[lane] + ALPHA_FLAG * lf;
    }
}

__global__ __launch_bounds__(256) void agg_film_kernel(
    const __half* xh, const float* s_src, const float* s_dst, const int* row_ptr,
    const int* csr_src, const float* b_g, const int* batch, const float* gb_film,
    __half* xout_h, int N) {
    agg_impl<0>(xh, s_src, s_dst, row_ptr, csr_src, b_g, batch, gb_film, xout_h, N,
                nullptr, nullptr, nullptr, nullptr, nullptr, nullptr, nullptr,
                nullptr, nullptr, nullptr);
}

__global__ __launch_bounds__(256) void agg_cls_kernel(
    const __half* xh, const float* s_src, const float* s_dst, const int* row_ptr,
    const int* csr_src, const float* b_g, int N, const float* x_all,
    const float* W_cl1, const float* b_cl1, const float* W_cl2, const float* b_cl2,
    const float* W_fh1, const float* b_fh1, const float* W_fh2, const float* b_fh2,
    float* out) {
    agg_impl<1>(xh, s_src, s_dst, row_ptr, csr_src, b_g, nullptr, nullptr, nullptr, N,
                x_all, W_cl1, b_cl1, W_cl2, b_cl2, W_fh1, b_fh1, W_fh2, b_fh2, out);
}

extern "C" void kernel_launch(void* const* d_in, const int* in_sizes, int n_in,
                              void* d_out, int out_size, void* d_ws, size_t ws_size,
                              hipStream_t stream) {
    const float* x_all   = (const float*)d_in[0];
    const float* climber = (const float*)d_in[1];
    const int*   eidx    = (const int*)d_in[2];
    const int*   batch   = (const int*)d_in[3];
    const float* W_in  = (const float*)d_in[4];
    const float* b_in  = (const float*)d_in[5];
    const float* W_c   = (const float*)d_in[6];
    const float* b_c   = (const float*)d_in[7];
    const float* W_f1  = (const float*)d_in[8];
    const float* b_f1  = (const float*)d_in[9];
    const float* W_f2  = (const float*)d_in[10];
    const float* b_f2  = (const float*)d_in[11];
    const float* W_g1  = (const float*)d_in[12];
    const float* a_s1  = (const float*)d_in[13];
    const float* a_d1  = (const float*)d_in[14];
    const float* b_g1  = (const float*)d_in[15];
    const float* W_g2  = (const float*)d_in[16];
    const float* a_s2  = (const float*)d_in[17];
    const float* a_d2  = (const float*)d_in[18];
    const float* b_g2  = (const float*)d_in[19];
    const float* W_cl1 = (const float*)d_in[20];
    const float* b_cl1 = (const float*)d_in[21];
    const float* W_cl2 = (const float*)d_in[22];
    const float* b_cl2 = (const float*)d_in[23];
    const float* W_fh1 = (const float*)d_in[24];
    const float* b_fh1 = (const float*)d_in[25];
    const float* W_fh2 = (const float*)d_in[26];
    const float* b_fh2 = (const float*)d_in[27];
    float* out = (float*)d_out;

    const int N = in_sizes[0] / 8;      // 50000
    const int E = in_sizes[2] / 2;      // 800000 (even)
    const int G = in_sizes[1] / 4;      // 128
    const int* src = eidx;
    const int* dst = eidx + E;
    const int NB_SCAN = (N + SCAN_CHUNK - 1) / SCAN_CHUNK;   // 49

    char* ws = (char*)d_ws;
    size_t off = 0;
    auto alloc = [&](size_t bytes) { char* p = ws + off; off += align256(bytes); return p; };
    float*  gb1     = (float*)alloc((size_t)G * 128 * 4);
    float*  gb2     = (float*)alloc((size_t)G * 128 * 4);
    __half* xbuf    = (__half*)alloc((size_t)N * 64 * 2);
    __half* xh      = (__half*)alloc((size_t)N * 128 * 2);
    float*  s_src   = (float*)alloc((size_t)N * 2 * 4);
    float*  s_dst   = (float*)alloc((size_t)N * 2 * 4);
    int*    counts  = (int*)alloc((size_t)N * 4);
    int*    ranks   = (int*)alloc((size_t)E * 4);
    int*    row_ptr = (int*)alloc((size_t)(N + 1) * 4);
    int*    csr_src = (int*)alloc((size_t)(E + N) * 4);
    (void)ws_size;

    // 1. FiLM params
    prep_kernel<<<G, 128, 0, stream>>>(climber, W_c, b_c, W_f1, b_f1, W_f2, b_f2, gb1, gb2);
    // 2. CSR build (shared by both layers; scatter is atomic-free via ranks)
    hipMemsetAsync(counts, 0, (size_t)N * 4, stream);
    hist_kernel<<<(E / 4 + 255) / 256, 256, 0, stream>>>(dst, E, counts, ranks);
    scan_kernel<<<NB_SCAN, 256, 0, stream>>>(counts, row_ptr, N);
    scatter_kernel<<<(E / 2 + N + 255) / 256, 256, 0, stream>>>(src, dst, ranks, counts,
                                                                row_ptr, E / 2, N, csr_src);
    // 3. GAT layer 1 (input transform + FiLM1 fused into xh; +relu, +FiLM2 in agg)
    xh_kernel<<<(N + XH_NB - 1) / XH_NB, 256, 0, stream>>>(nullptr, W_g1, a_s1, a_d1, xh,
                                                           s_src, s_dst, N, 1,
                                                           x_all, batch, W_in, b_in, gb1);
    agg_film_kernel<<<(N * 64 + 255) / 256, 256, 0, stream>>>(xh, s_src, s_dst, row_ptr, csr_src,
                                                              b_g1, batch, gb2, xbuf, N);
    // 4. GAT layer 2 (+relu) fused with classifier + flag head
    xh_kernel<<<(N + XH_NB - 1) / XH_NB, 256, 0, stream>>>(xbuf, W_g2, a_s2, a_d2, xh,
                                                           s_src, s_dst, N, 0,
                                                           nullptr, nullptr, nullptr, nullptr, nullptr);
    agg_cls_kernel<<<(N * 64 + 255) / 256, 256, 0, stream>>>(xh, s_src, s_dst, row_ptr, csr_src,
                                                             b_g2, N, x_all, W_cl1, b_cl1,
                                                             W_cl2, b_cl2, W_fh1, b_fh1,
                                                             W_fh2, b_fh2, out);
}

// Round 12
// 223.686 us; speedup vs baseline: 1.1752x; 1.0221x over previous
//
#include <hip/hip_runtime.h>
#include <hip/hip_fp16.h>

#define NEG_SLOPE 0.2f
#define ALPHA_FLAG 0.05f

typedef _Float16 h2t __attribute__((ext_vector_type(2)));
union h2u { unsigned u; h2t h; __half2 hh; float f; };
static __device__ __forceinline__ h2t u_as_h2(unsigned u) { h2u c; c.u = u; return c.h; }
static __device__ __forceinline__ float h2_as_f(__half2 h) { h2u c; c.hh = h; return c.f; }
static __device__ __forceinline__ h2t f_as_h2(float f) { h2u c; c.f = f; return c.h; }

static inline size_t align256(size_t x) { return (x + 255) & ~(size_t)255; }

// ---------- tiny prep: c = relu(climber@W_c + b_c); gb = c@W_f + b_f ----------
__global__ void prep_kernel(const float* __restrict__ climber,
                            const float* __restrict__ W_c, const float* __restrict__ b_c,
                            const float* __restrict__ W_f1, const float* __restrict__ b_f1,
                            const float* __restrict__ W_f2, const float* __restrict__ b_f2,
                            float* __restrict__ gb1, float* __restrict__ gb2) {
    __shared__ float c_sh[64];
    int g = blockIdx.x, t = threadIdx.x;   // block: 128 threads
    if (t < 64) {
        float acc = b_c[t];
#pragma unroll
        for (int k = 0; k < 4; ++k) acc = fmaf(climber[g * 4 + k], W_c[k * 64 + t], acc);
        c_sh[t] = fmaxf(acc, 0.f);
    }
    __syncthreads();
    float a1 = b_f1[t], a2 = b_f2[t];
#pragma unroll 8
    for (int h = 0; h < 64; ++h) {
        float cv = c_sh[h];
        a1 = fmaf(cv, W_f1[h * 128 + t], a1);
        a2 = fmaf(cv, W_f2[h * 128 + t], a2);
    }
    gb1[g * 128 + t] = a1;
    gb2[g * 128 + t] = a2;
}

// ---------- CSR build ----------
// counts zeroed by hipMemsetAsync. hist also records each edge's within-row rank
// (the atomicAdd return), making the scatter pass atomic-free.
__global__ void hist_kernel(const int* __restrict__ dst, int E,
                            int* __restrict__ counts, int* __restrict__ ranks) {
    int i4 = (blockIdx.x * blockDim.x + threadIdx.x) * 4;
    if (i4 + 3 < E) {
        int4 d = *(const int4*)&dst[i4];
        int4 r;
        r.x = atomicAdd(&counts[d.x], 1);
        r.y = atomicAdd(&counts[d.y], 1);
        r.z = atomicAdd(&counts[d.z], 1);
        r.w = atomicAdd(&counts[d.w], 1);
        *(int4*)&ranks[i4] = r;
    } else {
        for (int u = 0; u < 4; ++u)
            if (i4 + u < E) ranks[i4 + u] = atomicAdd(&counts[dst[i4 + u]], 1);
    }
}

// single-pass scan: block b computes its own prefix (sum of preceding full chunks),
// then local chunk scan. Self-loop +1 per node folded in. Writes row_ptr only.
#define SCAN_CHUNK 1024
__global__ void scan_kernel(const int* __restrict__ counts, int* __restrict__ row_ptr, int N) {
    __shared__ int sh[256];
    int b = blockIdx.x, t = threadIdx.x;
    // prefix over preceding chunks (all full: b*1024 <= N for every non-last block boundary)
    int pre = 0;
    for (int i0 = t * 4; i0 < b * SCAN_CHUNK; i0 += 1024) {
        int4 v = *(const int4*)&counts[i0];
        pre += v.x + v.y + v.z + v.w + 4;   // +1 self-loop each
    }
    sh[t] = pre;
    __syncthreads();
#pragma unroll
    for (int off = 128; off; off >>= 1) {
        if (t < off) sh[t] += sh[t + off];
        __syncthreads();
    }
    int base = sh[0];
    __syncthreads();
    // local chunk scan
    int idx0 = b * SCAN_CHUNK + t * 4;
    int c[4];
    if (idx0 + 3 < N) {
        int4 v = *(const int4*)&counts[idx0];
        c[0] = v.x + 1; c[1] = v.y + 1; c[2] = v.z + 1; c[3] = v.w + 1;
    } else {
#pragma unroll
        for (int u = 0; u < 4; ++u) c[u] = (idx0 + u < N) ? counts[idx0 + u] + 1 : 0;
    }
    int s = c[0] + c[1] + c[2] + c[3];
    sh[t] = s;
    __syncthreads();
#pragma unroll
    for (int off = 1; off < 256; off <<= 1) {
        int add = (t >= off) ? sh[t - off] : 0;
        __syncthreads();
        sh[t] += add;
        __syncthreads();
    }
    int run = base + sh[t] - s;
#pragma unroll
    for (int u = 0; u < 4; ++u) {
        if (idx0 + u < N) {
            row_ptr[idx0 + u] = run;
            run += c[u];
            if (idx0 + u == N - 1) row_ptr[N] = run;
        }
    }
}

// atomic-free scatter: pos = row_ptr[dst] + rank; self-loop at row_ptr[n] + counts[n]
__global__ void scatter_kernel(const int* __restrict__ src, const int* __restrict__ dst,
                               const int* __restrict__ ranks, const int* __restrict__ counts,
                               const int* __restrict__ row_ptr,
                               int Eh, int N, int* __restrict__ csr_src) {
    int t = blockIdx.x * blockDim.x + threadIdx.x;   // Eh = E/2 (E even)
    if (t < Eh) {
        int2 s2 = *(const int2*)&src[t * 2];
        int2 d2 = *(const int2*)&dst[t * 2];
        int2 r2 = *(const int2*)&ranks[t * 2];
        csr_src[row_ptr[d2.x] + r2.x] = s2.x;
        csr_src[row_ptr[d2.y] + r2.y] = s2.y;
    } else {
        int i = t - Eh;
        if (i < N) csr_src[row_ptr[i] + counts[i]] = i;   // self-loop (last slot)
    }
}

// ---------- per-layer: xh = x@W_g (fp16 out, [n][c][h] interleaved); scores ----------
// in_mode=1: compute x on the fly from x_all (input transform + FiLM1), layer 1
// in_mode=0: load x (fp16) from xbuf (layer 2)
#define XH_NB 32
__global__ __launch_bounds__(256, 4) void xh_kernel(
    const __half* __restrict__ xhalf, const float* __restrict__ W_g,
    const float* __restrict__ a_src, const float* __restrict__ a_dst,
    __half* __restrict__ xh, float* __restrict__ s_src, float* __restrict__ s_dst,
    int N, int in_mode,
    const float* __restrict__ x_all, const int* __restrict__ batch,
    const float* __restrict__ W_in, const float* __restrict__ b_in,
    const float* __restrict__ gb1) {
    __shared__ float x_sh[XH_NB * 64];   // 8 KB
    __shared__ float win_sh[6 * 64 + 64];
    int t = threadIdx.x;
    int base = blockIdx.x * XH_NB;
    if (in_mode) {
        for (int i = t; i < 448; i += 256)
            win_sh[i] = (i < 384) ? W_in[i] : b_in[i - 384];
        __syncthreads();
        int nd = t >> 3;            // node in tile: 0..31
        int jb = (t & 7) * 8;       // output channel block
        int n = base + nd;
        if (n < N) {
            float4 a = *(const float4*)&x_all[(size_t)n * 8];
            float2 b = *(const float2*)&x_all[(size_t)n * 8 + 4];
            float xa[6] = {a.x, a.y, a.z, a.w, b.x, b.y};
            int g = batch[n];
            const float* gbrow = &gb1[g * 128];
#pragma unroll
            for (int jj = 0; jj < 8; ++jj) {
                int j = jb + jj;
                float acc = win_sh[384 + j];
#pragma unroll
                for (int k = 0; k < 6; ++k) acc = fmaf(xa[k], win_sh[k * 64 + j], acc);
                x_sh[nd * 64 + j] = acc * (1.f + gbrow[j]) + gbrow[64 + j];
            }
        } else {
#pragma unroll
            for (int jj = 0; jj < 8; ++jj) x_sh[nd * 64 + jb + jj] = 0.f;
        }
    } else {
        int nvalid = N - base; if (nvalid > XH_NB) nvalid = XH_NB;
        int nhalves = nvalid * 64;   // multiple of 64; t*8 either fully in or out
        int idx = t * 8;
        uint4 raw = make_uint4(0, 0, 0, 0);
        if (idx < nhalves) raw = *(const uint4*)&xhalf[(size_t)base * 64 + idx];
        float2 f0 = __half22float2(*(__half2*)&raw.x);
        float2 f1 = __half22float2(*(__half2*)&raw.y);
        float2 f2 = __half22float2(*(__half2*)&raw.z);
        float2 f3 = __half22float2(*(__half2*)&raw.w);
        x_sh[idx + 0] = f0.x; x_sh[idx + 1] = f0.y;
        x_sh[idx + 2] = f1.x; x_sh[idx + 3] = f1.y;
        x_sh[idx + 4] = f2.x; x_sh[idx + 5] = f2.y;
        x_sh[idx + 6] = f3.x; x_sh[idx + 7] = f3.y;
    }
    __syncthreads();
    int c = t & 63;     // channel within head
    int g = t >> 6;     // wave id: handles nodes g*8..g*8+7, both heads
    float acc0[8], acc1[8];
#pragma unroll
    for (int i = 0; i < 8; ++i) { acc0[i] = 0.f; acc1[i] = 0.f; }
    const float* W0 = W_g + c;
    const float* W1 = W_g + 64 + c;
#pragma unroll 2
    for (int k = 0; k < 64; k += 4) {
        float w0[4], w1[4];
#pragma unroll
        for (int u = 0; u < 4; ++u) { w0[u] = W0[(k + u) * 128]; w1[u] = W1[(k + u) * 128]; }
#pragma unroll
        for (int i = 0; i < 8; ++i) {
            float4 xv = *(const float4*)&x_sh[(g * 8 + i) * 64 + k];
            acc0[i] = fmaf(xv.x, w0[0], acc0[i]);
            acc0[i] = fmaf(xv.y, w0[1], acc0[i]);
            acc0[i] = fmaf(xv.z, w0[2], acc0[i]);
            acc0[i] = fmaf(xv.w, w0[3], acc0[i]);
            acc1[i] = fmaf(xv.x, w1[0], acc1[i]);
            acc1[i] = fmaf(xv.y, w1[1], acc1[i]);
            acc1[i] = fmaf(xv.z, w1[2], acc1[i]);
            acc1[i] = fmaf(xv.w, w1[3], acc1[i]);
        }
    }
    float as0 = a_src[c], ad0 = a_dst[c];
    float as1 = a_src[64 + c], ad1 = a_dst[64 + c];
#pragma unroll
    for (int i = 0; i < 8; ++i) {
        int n = base + g * 8 + i;
        float ps0 = acc0[i] * as0, pd0 = acc0[i] * ad0;
        float ps1 = acc1[i] * as1, pd1 = acc1[i] * ad1;
#pragma unroll
        for (int off = 32; off; off >>= 1) {
            ps0 += __shfl_xor(ps0, off); pd0 += __shfl_xor(pd0, off);
            ps1 += __shfl_xor(ps1, off); pd1 += __shfl_xor(pd1, off);
        }
        if (n < N) {
            if (c == 0) {
                s_src[n * 2 + 0] = ps0; s_src[n * 2 + 1] = ps1;
                s_dst[n * 2 + 0] = pd0; s_dst[n * 2 + 1] = pd1;
            }
            __half2 hv = __floats2half2_rn(acc0[i], acc1[i]);
            *(__half2*)&xh[(size_t)n * 128 + c * 2] = hv;
        }
    }
}

// dot2 helper: acc += w.h0*x.h0 + w.h1*x.h1 (fp32 accumulate)
static __device__ __forceinline__ float dot2acc(unsigned xbits, h2t w, float acc) {
#if __has_builtin(__builtin_amdgcn_fdot2)
    return __builtin_amdgcn_fdot2(u_as_h2(xbits), w, acc, false);
#else
    h2u cx; cx.u = xbits;
    float2 xf = __half22float2(cx.hh);
    h2u cw; cw.h = w;
    float2 wf = __half22float2(cw.hh);
    return fmaf(xf.x, wf.x, fmaf(xf.y, wf.y, acc));
#endif
}

// ---------- wave-per-node aggregation core (dot2, pre-normalized softmax) ----------
// j-loops carry `#pragma unroll 4`: batches 4 ds_reads + 4 global gathers in
// flight before the first dot2 group (ILP for the latency-bound gather).
template <int MODE>
static __device__ __forceinline__ void agg_impl(
    const __half* __restrict__ xh, const float* __restrict__ s_src,
    const float* __restrict__ s_dst, const int* __restrict__ row_ptr,
    const int* __restrict__ csr_src, const float* __restrict__ b_g,
    const int* __restrict__ batch, const float* __restrict__ gb_film,
    __half* __restrict__ xout_h, int N,
    const float* __restrict__ x_all,
    const float* __restrict__ W_cl1, const float* __restrict__ b_cl1,
    const float* __restrict__ W_cl2, const float* __restrict__ b_cl2,
    const float* __restrict__ W_fh1, const float* __restrict__ b_fh1,
    const float* __restrict__ W_fh2, const float* __restrict__ b_fh2,
    float* __restrict__ out) {
    __shared__ float2 ps_sh[4][64];   // (packed half2 alpha, row byte-offset)
    __shared__ float vh_sh[4][64];
    int lane = threadIdx.x & 63;
    int w = threadIdx.x >> 6;
    int n = (blockIdx.x * blockDim.x + threadIdx.x) >> 6;
    if (n >= N) return;
    int beg = row_ptr[n], end = row_ptr[n + 1];
    int deg = end - beg;
    float2 sd = *(const float2*)&s_dst[n * 2];
    const char* xhb = (const char*)xh;
    int sub = lane >> 4;
    unsigned q16 = (unsigned)(lane & 15) * 16u;
    float acc[4] = {0.f, 0.f, 0.f, 0.f};

    if (deg <= 64) {
        float p0 = 0.f, p1 = 0.f; unsigned sb = 0;
        if (lane < deg) {
            int s = csr_src[beg + lane];
            sb = (unsigned)s << 8;
            float2 ss = *(const float2*)&s_src[s * 2];
            float e0 = ss.x + sd.x, e1 = ss.y + sd.y;
            e0 = (e0 > 0.f) ? e0 : NEG_SLOPE * e0;
            e1 = (e1 > 0.f) ? e1 : NEG_SLOPE * e1;
            p0 = __expf(e0); p1 = __expf(e1);
        }
        float dp0 = p0, dp1 = p1;
#pragma unroll
        for (int off = 32; off; off >>= 1) {
            dp0 += __shfl_xor(dp0, off);
            dp1 += __shfl_xor(dp1, off);
        }
        float i0 = 0.5f / (dp0 + 1e-16f), i1 = 0.5f / (dp1 + 1e-16f);
        ps_sh[w][lane] = make_float2(h2_as_f(__floats2half2_rn(p0 * i0, p1 * i1)),
                                     __uint_as_float(sb));
        int mr = (deg + 3) & ~3;
#pragma unroll 4
        for (int j = 0; j < mr; j += 4) {
            float2 ps = ps_sh[w][j + sub];                   // broadcast x4
            h2t wpk = f_as_h2(ps.x);
            unsigned voff = __float_as_uint(ps.y) + q16;
            uint4 hv = *(const uint4*)(xhb + voff);          // 4 x half2
            acc[0] = dot2acc(hv.x, wpk, acc[0]);
            acc[1] = dot2acc(hv.y, wpk, acc[1]);
            acc[2] = dot2acc(hv.z, wpk, acc[2]);
            acc[3] = dot2acc(hv.w, wpk, acc[3]);
        }
    } else {
        float dp0 = 0.f, dp1 = 0.f;
        for (int chunk = beg; chunk < end; chunk += 64) {
            int m = end - chunk; if (m > 64) m = 64;
            if (lane < m) {
                int s = csr_src[chunk + lane];
                float2 ss = *(const float2*)&s_src[s * 2];
                float e0 = ss.x + sd.x, e1 = ss.y + sd.y;
                e0 = (e0 > 0.f) ? e0 : NEG_SLOPE * e0;
                e1 = (e1 > 0.f) ? e1 : NEG_SLOPE * e1;
                dp0 += __expf(e0); dp1 += __expf(e1);
            }
        }
#pragma unroll
        for (int off = 32; off; off >>= 1) {
            dp0 += __shfl_xor(dp0, off);
            dp1 += __shfl_xor(dp1, off);
        }
        float i0 = 0.5f / (dp0 + 1e-16f), i1 = 0.5f / (dp1 + 1e-16f);
        for (int chunk = beg; chunk < end; chunk += 64) {
            int m = end - chunk; if (m > 64) m = 64;
            float p0 = 0.f, p1 = 0.f; unsigned sb = 0;
            if (lane < m) {
                int s = csr_src[chunk + lane];
                sb = (unsigned)s << 8;
                float2 ss = *(const float2*)&s_src[s * 2];
                float e0 = ss.x + sd.x, e1 = ss.y + sd.y;
                e0 = (e0 > 0.f) ? e0 : NEG_SLOPE * e0;
                e1 = (e1 > 0.f) ? e1 : NEG_SLOPE * e1;
                p0 = __expf(e0); p1 = __expf(e1);
            }
            ps_sh[w][lane] = make_float2(h2_as_f(__floats2half2_rn(p0 * i0, p1 * i1)),
                                         __uint_as_float(sb));
            int mr = (m + 3) & ~3;
#pragma unroll 4
            for (int j = 0; j < mr; j += 4) {
                float2 ps = ps_sh[w][j + sub];
                h2t wpk = f_as_h2(ps.x);
                unsigned voff = __float_as_uint(ps.y) + q16;
                uint4 hv = *(const uint4*)(xhb + voff);
                acc[0] = dot2acc(hv.x, wpk, acc[0]);
                acc[1] = dot2acc(hv.y, wpk, acc[1]);
                acc[2] = dot2acc(hv.z, wpk, acc[2]);
                acc[3] = dot2acc(hv.w, wpk, acc[3]);
            }
        }
    }
#pragma unroll
    for (int u = 0; u < 4; ++u) {
        acc[u] += __shfl_xor(acc[u], 16);
        acc[u] += __shfl_xor(acc[u], 32);
    }
    if (lane < 16) *(float4*)&vh_sh[w][lane * 4] = make_float4(acc[0], acc[1], acc[2], acc[3]);
    float v = vh_sh[w][lane] + b_g[lane];
    v = fmaxf(v, 0.f);
    if (MODE == 0) {
        int g = batch[n];
        v = v * (1.f + gb_film[g * 128 + lane]) + gb_film[g * 128 + 64 + lane];
        xout_h[(size_t)n * 64 + lane] = __float2half(v);
        return;
    }
    // ---- fused classifier ----
    vh_sh[w][lane] = v;
    float h = b_cl1[lane];
#pragma unroll 4
    for (int k = 0; k < 64; k += 4) {
        float4 vq = *(const float4*)&vh_sh[w][k];
        h = fmaf(vq.x, W_cl1[(k + 0) * 64 + lane], h);
        h = fmaf(vq.y, W_cl1[(k + 1) * 64 + lane], h);
        h = fmaf(vq.z, W_cl1[(k + 2) * 64 + lane], h);
        h = fmaf(vq.w, W_cl1[(k + 3) * 64 + lane], h);
    }
    h = fmaxf(h, 0.f);
    float4 w2 = *(const float4*)&W_cl2[lane * 4];
    float o0 = h * w2.x, o1 = h * w2.y, o2 = h * w2.z, o3 = h * w2.w;
#pragma unroll
    for (int off = 32; off; off >>= 1) {
        o0 += __shfl_xor(o0, off); o1 += __shfl_xor(o1, off);
        o2 += __shfl_xor(o2, off); o3 += __shfl_xor(o3, off);
    }
    if (lane < 4) {
        float f0 = x_all[(size_t)n * 8 + 6], f1 = x_all[(size_t)n * 8 + 7];
        float lf = b_fh2[lane];
#pragma unroll
        for (int m = 0; m < 8; ++m) {
            float fm = fmaxf(fmaf(f0, W_fh1[m], fmaf(f1, W_fh1[8 + m], b_fh1[m])), 0.f);
            lf = fmaf(fm, W_fh2[m * 4 + lane], lf);
        }
        float om = (lane == 0) ? o0 : (lane == 1) ? o1 : (lane == 2) ? o2 : o3;
        out[(size_t)n * 4 + lane] = om + b_cl2[lane] + ALPHA_FLAG * lf;
    }
}

__global__ __launch_bounds__(256) void agg_film_kernel(
    const __half* xh, const float* s_src, const float* s_dst, const int* row_ptr,
    const int* csr_src, const float* b_g, const int* batch, const float* gb_film,
    __half* xout_h, int N) {
    agg_impl<0>(xh, s_src, s_dst, row_ptr, csr_src, b_g, batch, gb_film, xout_h, N,
                nullptr, nullptr, nullptr, nullptr, nullptr, nullptr, nullptr,
                nullptr, nullptr, nullptr);
}

__global__ __launch_bounds__(256) void agg_cls_kernel(
    const __half* xh, const float* s_src, const float* s_dst, const int* row_ptr,
    const int* csr_src, const float* b_g, int N, const float* x_all,
    const float* W_cl1, const float* b_cl1, const float* W_cl2, const float* b_cl2,
    const float* W_fh1, const float* b_fh1, const float* W_fh2, const float* b_fh2,
    float* out) {
    agg_impl<1>(xh, s_src, s_dst, row_ptr, csr_src, b_g, nullptr, nullptr, nullptr, N,
                x_all, W_cl1, b_cl1, W_cl2, b_cl2, W_fh1, b_fh1, W_fh2, b_fh2, out);
}

extern "C" void kernel_launch(void* const* d_in, const int* in_sizes, int n_in,
                              void* d_out, int out_size, void* d_ws, size_t ws_size,
                              hipStream_t stream) {
    const float* x_all   = (const float*)d_in[0];
    const float* climber = (const float*)d_in[1];
    const int*   eidx    = (const int*)d_in[2];
    const int*   batch   = (const int*)d_in[3];
    const float* W_in  = (const float*)d_in[4];
    const float* b_in  = (const float*)d_in[5];
    const float* W_c   = (const float*)d_in[6];
    const float* b_c   = (const float*)d_in[7];
    const float* W_f1  = (const float*)d_in[8];
    const float* b_f1  = (const float*)d_in[9];
    const float* W_f2  = (const float*)d_in[10];
    const float* b_f2  = (const float*)d_in[11];
    const float* W_g1  = (const float*)d_in[12];
    const float* a_s1  = (const float*)d_in[13];
    const float* a_d1  = (const float*)d_in[14];
    const float* b_g1  = (const float*)d_in[15];
    const float* W_g2  = (const float*)d_in[16];
    const float* a_s2  = (const float*)d_in[17];
    const float* a_d2  = (const float*)d_in[18];
    const float* b_g2  = (const float*)d_in[19];
    const float* W_cl1 = (const float*)d_in[20];
    const float* b_cl1 = (const float*)d_in[21];
    const float* W_cl2 = (const float*)d_in[22];
    const float* b_cl2 = (const float*)d_in[23];
    const float* W_fh1 = (const float*)d_in[24];
    const float* b_fh1 = (const float*)d_in[25];
    const float* W_fh2 = (const float*)d_in[26];
    const float* b_fh2 = (const float*)d_in[27];
    float* out = (float*)d_out;

    const int N = in_sizes[0] / 8;      // 50000
    const int E = in_sizes[2] / 2;      // 800000 (even)
    const int G = in_sizes[1] / 4;      // 128
    const int* src = eidx;
    const int* dst = eidx + E;
    const int NB_SCAN = (N + SCAN_CHUNK - 1) / SCAN_CHUNK;   // 49

    char* ws = (char*)d_ws;
    size_t off = 0;
    auto alloc = [&](size_t bytes) { char* p = ws + off; off += align256(bytes); return p; };
    float*  gb1     = (float*)alloc((size_t)G * 128 * 4);
    float*  gb2     = (float*)alloc((size_t)G * 128 * 4);
    __half* xbuf    = (__half*)alloc((size_t)N * 64 * 2);
    __half* xh      = (__half*)alloc((size_t)N * 128 * 2);
    float*  s_src   = (float*)alloc((size_t)N * 2 * 4);
    float*  s_dst   = (float*)alloc((size_t)N * 2 * 4);
    int*    counts  = (int*)alloc((size_t)N * 4);
    int*    ranks   = (int*)alloc((size_t)E * 4);
    int*    row_ptr = (int*)alloc((size_t)(N + 1) * 4);
    int*    csr_src = (int*)alloc((size_t)(E + N) * 4);
    (void)ws_size;

    // 1. FiLM params
    prep_kernel<<<G, 128, 0, stream>>>(climber, W_c, b_c, W_f1, b_f1, W_f2, b_f2, gb1, gb2);
    // 2. CSR build (shared by both layers; scatter is atomic-free via ranks)
    hipMemsetAsync(counts, 0, (size_t)N * 4, stream);
    hist_kernel<<<(E / 4 + 255) / 256, 256, 0, stream>>>(dst, E, counts, ranks);
    scan_kernel<<<NB_SCAN, 256, 0, stream>>>(counts, row_ptr, N);
    scatter_kernel<<<(E / 2 + N + 255) / 256, 256, 0, stream>>>(src, dst, ranks, counts,
                                                                row_ptr, E / 2, N, csr_src);
    // 3. GAT layer 1 (input transform + FiLM1 fused into xh; +relu, +FiLM2 in agg)
    xh_kernel<<<(N + XH_NB - 1) / XH_NB, 256, 0, stream>>>(nullptr, W_g1, a_s1, a_d1, xh,
                                                           s_src, s_dst, N, 1,
                                                           x_all, batch, W_in, b_in, gb1);
    agg_film_kernel<<<(N * 64 + 255) / 256, 256, 0, stream>>>(xh, s_src, s_dst, row_ptr, csr_src,
                                                              b_g1, batch, gb2, xbuf, N);
    // 4. GAT layer 2 (+relu) fused with classifier + flag head
    xh_kernel<<<(N + XH_NB - 1) / XH_NB, 256, 0, stream>>>(xbuf, W_g2, a_s2, a_d2, xh,
                                                           s_src, s_dst, N, 0,
                                                           nullptr, nullptr, nullptr, nullptr, nullptr);
    agg_cls_kernel<<<(N * 64 + 255) / 256, 256, 0, stream>>>(xh, s_src, s_dst, row_ptr, csr_src,
                                                             b_g2, N, x_all, W_cl1, b_cl1,
                                                             W_cl2, b_cl2, W_fh1, b_fh1,
                                                             W_fh2, b_fh2, out);
}

// Round 13
// 220.706 us; speedup vs baseline: 1.1910x; 1.0135x over previous
//
#include <hip/hip_runtime.h>
#include <hip/hip_fp16.h>

#define NEG_SLOPE 0.2f
#define ALPHA_FLAG 0.05f

typedef _Float16 h2t __attribute__((ext_vector_type(2)));
union h2u { unsigned u; h2t h; __half2 hh; float f; };
static __device__ __forceinline__ h2t u_as_h2(unsigned u) { h2u c; c.u = u; return c.h; }
static __device__ __forceinline__ float h2_as_f(__half2 h) { h2u c; c.hh = h; return c.f; }
static __device__ __forceinline__ h2t f_as_h2(float f) { h2u c; c.f = f; return c.h; }

static inline size_t align256(size_t x) { return (x + 255) & ~(size_t)255; }

// ---------- tiny prep: c = relu(climber@W_c + b_c); gb = c@W_f + b_f ----------
__global__ void prep_kernel(const float* __restrict__ climber,
                            const float* __restrict__ W_c, const float* __restrict__ b_c,
                            const float* __restrict__ W_f1, const float* __restrict__ b_f1,
                            const float* __restrict__ W_f2, const float* __restrict__ b_f2,
                            float* __restrict__ gb1, float* __restrict__ gb2) {
    __shared__ float c_sh[64];
    int g = blockIdx.x, t = threadIdx.x;   // block: 128 threads
    if (t < 64) {
        float acc = b_c[t];
#pragma unroll
        for (int k = 0; k < 4; ++k) acc = fmaf(climber[g * 4 + k], W_c[k * 64 + t], acc);
        c_sh[t] = fmaxf(acc, 0.f);
    }
    __syncthreads();
    float a1 = b_f1[t], a2 = b_f2[t];
#pragma unroll 8
    for (int h = 0; h < 64; ++h) {
        float cv = c_sh[h];
        a1 = fmaf(cv, W_f1[h * 128 + t], a1);
        a2 = fmaf(cv, W_f2[h * 128 + t], a2);
    }
    gb1[g * 128 + t] = a1;
    gb2[g * 128 + t] = a2;
}

// ---------- CSR build ----------
__global__ void hist_kernel(const int* __restrict__ dst, int E,
                            int* __restrict__ counts, int* __restrict__ ranks) {
    int i4 = (blockIdx.x * blockDim.x + threadIdx.x) * 4;
    if (i4 + 3 < E) {
        int4 d = *(const int4*)&dst[i4];
        int4 r;
        r.x = atomicAdd(&counts[d.x], 1);
        r.y = atomicAdd(&counts[d.y], 1);
        r.z = atomicAdd(&counts[d.z], 1);
        r.w = atomicAdd(&counts[d.w], 1);
        *(int4*)&ranks[i4] = r;
    } else {
        for (int u = 0; u < 4; ++u)
            if (i4 + u < E) ranks[i4 + u] = atomicAdd(&counts[dst[i4 + u]], 1);
    }
}

#define SCAN_CHUNK 1024
__global__ void scan_kernel(const int* __restrict__ counts, int* __restrict__ row_ptr, int N) {
    __shared__ int sh[256];
    int b = blockIdx.x, t = threadIdx.x;
    int pre = 0;
    for (int i0 = t * 4; i0 < b * SCAN_CHUNK; i0 += 1024) {
        int4 v = *(const int4*)&counts[i0];
        pre += v.x + v.y + v.z + v.w + 4;   // +1 self-loop each
    }
    sh[t] = pre;
    __syncthreads();
#pragma unroll
    for (int off = 128; off; off >>= 1) {
        if (t < off) sh[t] += sh[t + off];
        __syncthreads();
    }
    int base = sh[0];
    __syncthreads();
    int idx0 = b * SCAN_CHUNK + t * 4;
    int c[4];
    if (idx0 + 3 < N) {
        int4 v = *(const int4*)&counts[idx0];
        c[0] = v.x + 1; c[1] = v.y + 1; c[2] = v.z + 1; c[3] = v.w + 1;
    } else {
#pragma unroll
        for (int u = 0; u < 4; ++u) c[u] = (idx0 + u < N) ? counts[idx0 + u] + 1 : 0;
    }
    int s = c[0] + c[1] + c[2] + c[3];
    sh[t] = s;
    __syncthreads();
#pragma unroll
    for (int off = 1; off < 256; off <<= 1) {
        int add = (t >= off) ? sh[t - off] : 0;
        __syncthreads();
        sh[t] += add;
        __syncthreads();
    }
    int run = base + sh[t] - s;
#pragma unroll
    for (int u = 0; u < 4; ++u) {
        if (idx0 + u < N) {
            row_ptr[idx0 + u] = run;
            run += c[u];
            if (idx0 + u == N - 1) row_ptr[N] = run;
        }
    }
}

__global__ void scatter_kernel(const int* __restrict__ src, const int* __restrict__ dst,
                               const int* __restrict__ ranks, const int* __restrict__ counts,
                               const int* __restrict__ row_ptr,
                               int Eh, int N, int* __restrict__ csr_src) {
    int t = blockIdx.x * blockDim.x + threadIdx.x;   // Eh = E/2 (E even)
    if (t < Eh) {
        int2 s2 = *(const int2*)&src[t * 2];
        int2 d2 = *(const int2*)&dst[t * 2];
        int2 r2 = *(const int2*)&ranks[t * 2];
        csr_src[row_ptr[d2.x] + r2.x] = s2.x;
        csr_src[row_ptr[d2.y] + r2.y] = s2.y;
    } else {
        int i = t - Eh;
        if (i < N) csr_src[row_ptr[i] + counts[i]] = i;   // self-loop (last slot)
    }
}

// ---------- per-layer: xh = x@W_g (fp16 out, [n][c][h] interleaved); scores ----------
#define XH_NB 32
__global__ __launch_bounds__(256, 4) void xh_kernel(
    const __half* __restrict__ xhalf, const float* __restrict__ W_g,
    const float* __restrict__ a_src, const float* __restrict__ a_dst,
    __half* __restrict__ xh, float* __restrict__ s_src, float* __restrict__ s_dst,
    int N, int in_mode,
    const float* __restrict__ x_all, const int* __restrict__ batch,
    const float* __restrict__ W_in, const float* __restrict__ b_in,
    const float* __restrict__ gb1) {
    __shared__ float x_sh[XH_NB * 64];   // 8 KB
    __shared__ float win_sh[6 * 64 + 64];
    int t = threadIdx.x;
    int base = blockIdx.x * XH_NB;
    if (in_mode) {
        for (int i = t; i < 448; i += 256)
            win_sh[i] = (i < 384) ? W_in[i] : b_in[i - 384];
        __syncthreads();
        int nd = t >> 3;            // node in tile: 0..31
        int jb = (t & 7) * 8;       // output channel block
        int n = base + nd;
        if (n < N) {
            float4 a = *(const float4*)&x_all[(size_t)n * 8];
            float2 b = *(const float2*)&x_all[(size_t)n * 8 + 4];
            float xa[6] = {a.x, a.y, a.z, a.w, b.x, b.y};
            int g = batch[n];
            const float* gbrow = &gb1[g * 128];
#pragma unroll
            for (int jj = 0; jj < 8; ++jj) {
                int j = jb + jj;
                float acc = win_sh[384 + j];
#pragma unroll
                for (int k = 0; k < 6; ++k) acc = fmaf(xa[k], win_sh[k * 64 + j], acc);
                x_sh[nd * 64 + j] = acc * (1.f + gbrow[j]) + gbrow[64 + j];
            }
        } else {
#pragma unroll
            for (int jj = 0; jj < 8; ++jj) x_sh[nd * 64 + jb + jj] = 0.f;
        }
    } else {
        int nvalid = N - base; if (nvalid > XH_NB) nvalid = XH_NB;
        int nhalves = nvalid * 64;   // multiple of 64; t*8 either fully in or out
        int idx = t * 8;
        uint4 raw = make_uint4(0, 0, 0, 0);
        if (idx < nhalves) raw = *(const uint4*)&xhalf[(size_t)base * 64 + idx];
        float2 f0 = __half22float2(*(__half2*)&raw.x);
        float2 f1 = __half22float2(*(__half2*)&raw.y);
        float2 f2 = __half22float2(*(__half2*)&raw.z);
        float2 f3 = __half22float2(*(__half2*)&raw.w);
        x_sh[idx + 0] = f0.x; x_sh[idx + 1] = f0.y;
        x_sh[idx + 2] = f1.x; x_sh[idx + 3] = f1.y;
        x_sh[idx + 4] = f2.x; x_sh[idx + 5] = f2.y;
        x_sh[idx + 6] = f3.x; x_sh[idx + 7] = f3.y;
    }
    __syncthreads();
    int c = t & 63;     // channel within head
    int g = t >> 6;     // wave id: handles nodes g*8..g*8+7, both heads
    float acc0[8], acc1[8];
#pragma unroll
    for (int i = 0; i < 8; ++i) { acc0[i] = 0.f; acc1[i] = 0.f; }
    const float* W0 = W_g + c;
    const float* W1 = W_g + 64 + c;
#pragma unroll 2
    for (int k = 0; k < 64; k += 4) {
        float w0[4], w1[4];
#pragma unroll
        for (int u = 0; u < 4; ++u) { w0[u] = W0[(k + u) * 128]; w1[u] = W1[(k + u) * 128]; }
#pragma unroll
        for (int i = 0; i < 8; ++i) {
            float4 xv = *(const float4*)&x_sh[(g * 8 + i) * 64 + k];
            acc0[i] = fmaf(xv.x, w0[0], acc0[i]);
            acc0[i] = fmaf(xv.y, w0[1], acc0[i]);
            acc0[i] = fmaf(xv.z, w0[2], acc0[i]);
            acc0[i] = fmaf(xv.w, w0[3], acc0[i]);
            acc1[i] = fmaf(xv.x, w1[0], acc1[i]);
            acc1[i] = fmaf(xv.y, w1[1], acc1[i]);
            acc1[i] = fmaf(xv.z, w1[2], acc1[i]);
            acc1[i] = fmaf(xv.w, w1[3], acc1[i]);
        }
    }
    float as0 = a_src[c], ad0 = a_dst[c];
    float as1 = a_src[64 + c], ad1 = a_dst[64 + c];
#pragma unroll
    for (int i = 0; i < 8; ++i) {
        int n = base + g * 8 + i;
        float ps0 = acc0[i] * as0, pd0 = acc0[i] * ad0;
        float ps1 = acc1[i] * as1, pd1 = acc1[i] * ad1;
#pragma unroll
        for (int off = 32; off; off >>= 1) {
            ps0 += __shfl_xor(ps0, off); pd0 += __shfl_xor(pd0, off);
            ps1 += __shfl_xor(ps1, off); pd1 += __shfl_xor(pd1, off);
        }
        if (n < N) {
            if (c == 0) {
                s_src[n * 2 + 0] = ps0; s_src[n * 2 + 1] = ps1;
                s_dst[n * 2 + 0] = pd0; s_dst[n * 2 + 1] = pd1;
            }
            __half2 hv = __floats2half2_rn(acc0[i], acc1[i]);
            *(__half2*)&xh[(size_t)n * 128 + c * 2] = hv;
        }
    }
}

// dot2 helper: acc += w.h0*x.h0 + w.h1*x.h1 (fp32 accumulate)
static __device__ __forceinline__ float dot2acc(unsigned xbits, h2t w, float acc) {
#if __has_builtin(__builtin_amdgcn_fdot2)
    return __builtin_amdgcn_fdot2(u_as_h2(xbits), w, acc, false);
#else
    h2u cx; cx.u = xbits;
    float2 xf = __half22float2(cx.hh);
    h2u cw; cw.h = w;
    float2 wf = __half22float2(cw.hh);
    return fmaf(xf.x, wf.x, fmaf(xf.y, wf.y, acc));
#endif
}

// generic chunked single-node aggregation (any degree; used for rare deg>64)
static __device__ __forceinline__ void agg_one_slow(
    const char* __restrict__ xhb, const float* __restrict__ s_src,
    float2 sd, const int* __restrict__ csr_src, int beg, int end,
    int lane, int sub, unsigned q16, float2* __restrict__ ps_slot,
    float acc[4]) {
    float dp0 = 0.f, dp1 = 0.f;
    for (int chunk = beg; chunk < end; chunk += 64) {
        int m = end - chunk; if (m > 64) m = 64;
        if (lane < m) {
            int s = csr_src[chunk + lane];
            float2 ss = *(const float2*)&s_src[s * 2];
            float e0 = ss.x + sd.x, e1 = ss.y + sd.y;
            e0 = (e0 > 0.f) ? e0 : NEG_SLOPE * e0;
            e1 = (e1 > 0.f) ? e1 : NEG_SLOPE * e1;
            dp0 += __expf(e0); dp1 += __expf(e1);
        }
    }
#pragma unroll
    for (int off = 32; off; off >>= 1) {
        dp0 += __shfl_xor(dp0, off);
        dp1 += __shfl_xor(dp1, off);
    }
    float i0 = 0.5f / (dp0 + 1e-16f), i1 = 0.5f / (dp1 + 1e-16f);
    for (int chunk = beg; chunk < end; chunk += 64) {
        int m = end - chunk; if (m > 64) m = 64;
        float p0 = 0.f, p1 = 0.f; unsigned sb = 0;
        if (lane < m) {
            int s = csr_src[chunk + lane];
            sb = (unsigned)s << 8;
            float2 ss = *(const float2*)&s_src[s * 2];
            float e0 = ss.x + sd.x, e1 = ss.y + sd.y;
            e0 = (e0 > 0.f) ? e0 : NEG_SLOPE * e0;
            e1 = (e1 > 0.f) ? e1 : NEG_SLOPE * e1;
            p0 = __expf(e0); p1 = __expf(e1);
        }
        ps_slot[lane] = make_float2(h2_as_f(__floats2half2_rn(p0 * i0, p1 * i1)),
                                    __uint_as_float(sb));
        int mr = (m + 3) & ~3;
#pragma unroll 4
        for (int j = 0; j < mr; j += 4) {
            float2 ps = ps_slot[j + sub];
            h2t wpk = f_as_h2(ps.x);
            unsigned voff = __float_as_uint(ps.y) + q16;
            uint4 hv = *(const uint4*)(xhb + voff);
            acc[0] = dot2acc(hv.x, wpk, acc[0]);
            acc[1] = dot2acc(hv.y, wpk, acc[1]);
            acc[2] = dot2acc(hv.z, wpk, acc[2]);
            acc[3] = dot2acc(hv.w, wpk, acc[3]);
        }
    }
}

// ---------- wave-per-2-nodes aggregation (phase-interleaved dual pipeline) ----------
// Wave handles nodes n0 and n1 = n0 + half. Independent serial chains (csr gather,
// s_src gather, exp, reduce, xh gather) are issued interleaved -> 2x memory-level
// parallelism per wave. LDS slots zero-padded (p=0, sb=0) make the common
// max(mrA,mrB) gather trip exact (pad groups gather row 0 with alpha 0 = no-op).
// MODE 0: +bias, relu, FiLM -> fp16 xout. MODE 1: +bias, relu, classifier + flag.
template <int MODE>
static __device__ __forceinline__ void agg_impl(
    const __half* __restrict__ xh, const float* __restrict__ s_src,
    const float* __restrict__ s_dst, const int* __restrict__ row_ptr,
    const int* __restrict__ csr_src, const float* __restrict__ b_g,
    const int* __restrict__ batch, const float* __restrict__ gb_film,
    __half* __restrict__ xout_h, int N, int half,
    const float* __restrict__ x_all,
    const float* __restrict__ W_cl1, const float* __restrict__ b_cl1,
    const float* __restrict__ W_cl2, const float* __restrict__ b_cl2,
    const float* __restrict__ W_fh1, const float* __restrict__ b_fh1,
    const float* __restrict__ W_fh2, const float* __restrict__ b_fh2,
    float* __restrict__ out) {
    __shared__ float2 ps_sh[4][2][64];   // (packed half2 alpha, row byte-offset)
    __shared__ float vh_sh[4][2][64];
    int lane = threadIdx.x & 63;
    int w = threadIdx.x >> 6;
    int n0 = (blockIdx.x * blockDim.x + threadIdx.x) >> 6;
    if (n0 >= half) return;
    int n1 = n0 + half;
    bool valid1 = n1 < N;
    const char* xhb = (const char*)xh;
    int sub = lane >> 4;
    unsigned q16 = (unsigned)(lane & 15) * 16u;
    float accA[4] = {0.f, 0.f, 0.f, 0.f};
    float accB[4] = {0.f, 0.f, 0.f, 0.f};

    int begA = row_ptr[n0], endA = row_ptr[n0 + 1];
    int begB = valid1 ? row_ptr[n1] : 0, endB = valid1 ? row_ptr[n1 + 1] : 0;
    int degA = endA - begA, degB = endB - begB;
    float2 sdA = *(const float2*)&s_dst[n0 * 2];
    float2 sdB = valid1 ? *(const float2*)&s_dst[n1 * 2] : make_float2(0.f, 0.f);

    if (degA <= 64 && degB <= 64) {
        // ---- dual fast path: phase-interleaved ----
        int sA = (lane < degA) ? csr_src[begA + lane] : -1;
        int sB = (lane < degB) ? csr_src[begB + lane] : -1;
        float2 ssA = (sA >= 0) ? *(const float2*)&s_src[sA * 2] : make_float2(0.f, 0.f);
        float2 ssB = (sB >= 0) ? *(const float2*)&s_src[sB * 2] : make_float2(0.f, 0.f);
        float pA0 = 0.f, pA1 = 0.f, pB0 = 0.f, pB1 = 0.f;
        unsigned sbA = 0, sbB = 0;
        if (sA >= 0) {
            sbA = (unsigned)sA << 8;
            float e0 = ssA.x + sdA.x, e1 = ssA.y + sdA.y;
            e0 = (e0 > 0.f) ? e0 : NEG_SLOPE * e0;
            e1 = (e1 > 0.f) ? e1 : NEG_SLOPE * e1;
            pA0 = __expf(e0); pA1 = __expf(e1);
        }
        if (sB >= 0) {
            sbB = (unsigned)sB << 8;
            float e0 = ssB.x + sdB.x, e1 = ssB.y + sdB.y;
            e0 = (e0 > 0.f) ? e0 : NEG_SLOPE * e0;
            e1 = (e1 > 0.f) ? e1 : NEG_SLOPE * e1;
            pB0 = __expf(e0); pB1 = __expf(e1);
        }
        float dA0 = pA0, dA1 = pA1, dB0 = pB0, dB1 = pB1;
#pragma unroll
        for (int off = 32; off; off >>= 1) {   // 4 independent chains interleaved
            dA0 += __shfl_xor(dA0, off); dA1 += __shfl_xor(dA1, off);
            dB0 += __shfl_xor(dB0, off); dB1 += __shfl_xor(dB1, off);
        }
        float iA0 = 0.5f / (dA0 + 1e-16f), iA1 = 0.5f / (dA1 + 1e-16f);
        float iB0 = 0.5f / (dB0 + 1e-16f), iB1 = 0.5f / (dB1 + 1e-16f);
        ps_sh[w][0][lane] = make_float2(h2_as_f(__floats2half2_rn(pA0 * iA0, pA1 * iA1)),
                                        __uint_as_float(sbA));
        ps_sh[w][1][lane] = make_float2(h2_as_f(__floats2half2_rn(pB0 * iB0, pB1 * iB1)),
                                        __uint_as_float(sbB));
        int mrA = (degA + 3) & ~3, mrB = (degB + 3) & ~3;
        int mr = mrA > mrB ? mrA : mrB;
#pragma unroll 2
        for (int j = 0; j < mr; j += 4) {
            float2 psA = ps_sh[w][0][j + sub];
            float2 psB = ps_sh[w][1][j + sub];
            unsigned voA = __float_as_uint(psA.y) + q16;
            unsigned voB = __float_as_uint(psB.y) + q16;
            uint4 hvA = *(const uint4*)(xhb + voA);
            uint4 hvB = *(const uint4*)(xhb + voB);
            h2t wA = f_as_h2(psA.x), wB = f_as_h2(psB.x);
            accA[0] = dot2acc(hvA.x, wA, accA[0]);
            accA[1] = dot2acc(hvA.y, wA, accA[1]);
            accA[2] = dot2acc(hvA.z, wA, accA[2]);
            accA[3] = dot2acc(hvA.w, wA, accA[3]);
            accB[0] = dot2acc(hvB.x, wB, accB[0]);
            accB[1] = dot2acc(hvB.y, wB, accB[1]);
            accB[2] = dot2acc(hvB.z, wB, accB[2]);
            accB[3] = dot2acc(hvB.w, wB, accB[3]);
        }
    } else {
        // rare big-degree fallback: each node via generic chunked path
        agg_one_slow(xhb, s_src, sdA, csr_src, begA, endA, lane, sub, q16,
                     &ps_sh[w][0][0], accA);
        if (valid1)
            agg_one_slow(xhb, s_src, sdB, csr_src, begB, endB, lane, sub, q16,
                         &ps_sh[w][1][0], accB);
    }
#pragma unroll
    for (int u = 0; u < 4; ++u) {
        accA[u] += __shfl_xor(accA[u], 16);
        accA[u] += __shfl_xor(accA[u], 32);
        accB[u] += __shfl_xor(accB[u], 16);
        accB[u] += __shfl_xor(accB[u], 32);
    }
    if (lane < 16) {
        *(float4*)&vh_sh[w][0][lane * 4] = make_float4(accA[0], accA[1], accA[2], accA[3]);
        *(float4*)&vh_sh[w][1][lane * 4] = make_float4(accB[0], accB[1], accB[2], accB[3]);
    }
    float bg = b_g[lane];
    float vA = fmaxf(vh_sh[w][0][lane] + bg, 0.f);
    float vB = fmaxf(vh_sh[w][1][lane] + bg, 0.f);
    if (MODE == 0) {
        int gA = batch[n0];
        vA = vA * (1.f + gb_film[gA * 128 + lane]) + gb_film[gA * 128 + 64 + lane];
        xout_h[(size_t)n0 * 64 + lane] = __float2half(vA);
        if (valid1) {
            int gB = batch[n1];
            vB = vB * (1.f + gb_film[gB * 128 + lane]) + gb_film[gB * 128 + 64 + lane];
            xout_h[(size_t)n1 * 64 + lane] = __float2half(vB);
        }
        return;
    }
    // ---- fused classifier + flag head, per node ----
    vh_sh[w][0][lane] = vA;
    vh_sh[w][1][lane] = vB;
    float4 w2 = *(const float4*)&W_cl2[lane * 4];
    float b1v = b_cl1[lane];
    for (int q = 0; q < 2; ++q) {
        int n = q ? n1 : n0;
        if (q && !valid1) break;
        float h = b1v;
#pragma unroll 4
        for (int k = 0; k < 64; k += 4) {
            float4 vq = *(const float4*)&vh_sh[w][q][k];   // uniform broadcast
            h = fmaf(vq.x, W_cl1[(k + 0) * 64 + lane], h);
            h = fmaf(vq.y, W_cl1[(k + 1) * 64 + lane], h);
            h = fmaf(vq.z, W_cl1[(k + 2) * 64 + lane], h);
            h = fmaf(vq.w, W_cl1[(k + 3) * 64 + lane], h);
        }
        h = fmaxf(h, 0.f);
        float o0 = h * w2.x, o1 = h * w2.y, o2 = h * w2.z, o3 = h * w2.w;
#pragma unroll
        for (int off = 32; off; off >>= 1) {
            o0 += __shfl_xor(o0, off); o1 += __shfl_xor(o1, off);
            o2 += __shfl_xor(o2, off); o3 += __shfl_xor(o3, off);
        }
        if (lane < 4) {
            float f0 = x_all[(size_t)n * 8 + 6], f1 = x_all[(size_t)n * 8 + 7];
            float lf = b_fh2[lane];
#pragma unroll
            for (int m = 0; m < 8; ++m) {
                float fm = fmaxf(fmaf(f0, W_fh1[m], fmaf(f1, W_fh1[8 + m], b_fh1[m])), 0.f);
                lf = fmaf(fm, W_fh2[m * 4 + lane], lf);
            }
            float om = (lane == 0) ? o0 : (lane == 1) ? o1 : (lane == 2) ? o2 : o3;
            out[(size_t)n * 4 + lane] = om + b_cl2[lane] + ALPHA_FLAG * lf;
        }
    }
}

__global__ __launch_bounds__(256) void agg_film_kernel(
    const __half* xh, const float* s_src, const float* s_dst, const int* row_ptr,
    const int* csr_src, const float* b_g, const int* batch, const float* gb_film,
    __half* xout_h, int N, int half) {
    agg_impl<0>(xh, s_src, s_dst, row_ptr, csr_src, b_g, batch, gb_film, xout_h, N, half,
                nullptr, nullptr, nullptr, nullptr, nullptr, nullptr, nullptr,
                nullptr, nullptr, nullptr);
}

__global__ __launch_bounds__(256) void agg_cls_kernel(
    const __half* xh, const float* s_src, const float* s_dst, const int* row_ptr,
    const int* csr_src, const float* b_g, int N, int half, const float* x_all,
    const float* W_cl1, const float* b_cl1, const float* W_cl2, const float* b_cl2,
    const float* W_fh1, const float* b_fh1, const float* W_fh2, const float* b_fh2,
    float* out) {
    agg_impl<1>(xh, s_src, s_dst, row_ptr, csr_src, b_g, nullptr, nullptr, nullptr, N, half,
                x_all, W_cl1, b_cl1, W_cl2, b_cl2, W_fh1, b_fh1, W_fh2, b_fh2, out);
}

extern "C" void kernel_launch(void* const* d_in, const int* in_sizes, int n_in,
                              void* d_out, int out_size, void* d_ws, size_t ws_size,
                              hipStream_t stream) {
    const float* x_all   = (const float*)d_in[0];
    const float* climber = (const float*)d_in[1];
    const int*   eidx    = (const int*)d_in[2];
    const int*   batch   = (const int*)d_in[3];
    const float* W_in  = (const float*)d_in[4];
    const float* b_in  = (const float*)d_in[5];
    const float* W_c   = (const float*)d_in[6];
    const float* b_c   = (const float*)d_in[7];
    const float* W_f1  = (const float*)d_in[8];
    const float* b_f1  = (const float*)d_in[9];
    const float* W_f2  = (const float*)d_in[10];
    const float* b_f2  = (const float*)d_in[11];
    const float* W_g1  = (const float*)d_in[12];
    const float* a_s1  = (const float*)d_in[13];
    const float* a_d1  = (const float*)d_in[14];
    const float* b_g1  = (const float*)d_in[15];
    const float* W_g2  = (const float*)d_in[16];
    const float* a_s2  = (const float*)d_in[17];
    const float* a_d2  = (const float*)d_in[18];
    const float* b_g2  = (const float*)d_in[19];
    const float* W_cl1 = (const float*)d_in[20];
    const float* b_cl1 = (const float*)d_in[21];
    const float* W_cl2 = (const float*)d_in[22];
    const float* b_cl2 = (const float*)d_in[23];
    const float* W_fh1 = (const float*)d_in[24];
    const float* b_fh1 = (const float*)d_in[25];
    const float* W_fh2 = (const float*)d_in[26];
    const float* b_fh2 = (const float*)d_in[27];
    float* out = (float*)d_out;

    const int N = in_sizes[0] / 8;      // 50000
    const int E = in_sizes[2] / 2;      // 800000 (even)
    const int G = in_sizes[1] / 4;      // 128
    const int* src = eidx;
    const int* dst = eidx + E;
    const int NB_SCAN = (N + SCAN_CHUNK - 1) / SCAN_CHUNK;   // 49
    const int half = (N + 1) / 2;       // 25000

    char* ws = (char*)d_ws;
    size_t off = 0;
    auto alloc = [&](size_t bytes) { char* p = ws + off; off += align256(bytes); return p; };
    float*  gb1     = (float*)alloc((size_t)G * 128 * 4);
    float*  gb2     = (float*)alloc((size_t)G * 128 * 4);
    __half* xbuf    = (__half*)alloc((size_t)N * 64 * 2);
    __half* xh      = (__half*)alloc((size_t)N * 128 * 2);
    float*  s_src   = (float*)alloc((size_t)N * 2 * 4);
    float*  s_dst   = (float*)alloc((size_t)N * 2 * 4);
    int*    counts  = (int*)alloc((size_t)N * 4);
    int*    ranks   = (int*)alloc((size_t)E * 4);
    int*    row_ptr = (int*)alloc((size_t)(N + 1) * 4);
    int*    csr_src = (int*)alloc((size_t)(E + N) * 4);
    (void)ws_size;

    // 1. FiLM params
    prep_kernel<<<G, 128, 0, stream>>>(climber, W_c, b_c, W_f1, b_f1, W_f2, b_f2, gb1, gb2);
    // 2. CSR build (shared by both layers; scatter is atomic-free via ranks)
    hipMemsetAsync(counts, 0, (size_t)N * 4, stream);
    hist_kernel<<<(E / 4 + 255) / 256, 256, 0, stream>>>(dst, E, counts, ranks);
    scan_kernel<<<NB_SCAN, 256, 0, stream>>>(counts, row_ptr, N);
    scatter_kernel<<<(E / 2 + N + 255) / 256, 256, 0, stream>>>(src, dst, ranks, counts,
                                                                row_ptr, E / 2, N, csr_src);
    // 3. GAT layer 1 (input transform + FiLM1 fused into xh; +relu, +FiLM2 in agg)
    xh_kernel<<<(N + XH_NB - 1) / XH_NB, 256, 0, stream>>>(nullptr, W_g1, a_s1, a_d1, xh,
                                                           s_src, s_dst, N, 1,
                                                           x_all, batch, W_in, b_in, gb1);
    agg_film_kernel<<<(half * 64 + 255) / 256, 256, 0, stream>>>(xh, s_src, s_dst, row_ptr,
                                                                 csr_src, b_g1, batch, gb2,
                                                                 xbuf, N, half);
    // 4. GAT layer 2 (+relu) fused with classifier + flag head
    xh_kernel<<<(N + XH_NB - 1) / XH_NB, 256, 0, stream>>>(xbuf, W_g2, a_s2, a_d2, xh,
                                                           s_src, s_dst, N, 0,
                                                           nullptr, nullptr, nullptr, nullptr, nullptr);
    agg_cls_kernel<<<(half * 64 + 255) / 256, 256, 0, stream>>>(xh, s_src, s_dst, row_ptr,
                                                                csr_src, b_g2, N, half, x_all,
                                                                W_cl1, b_cl1, W_cl2, b_cl2,
                                                                W_fh1, b_fh1, W_fh2, b_fh2, out);
}

// Round 14
// 213.823 us; speedup vs baseline: 1.2294x; 1.0322x over previous
//
#include <hip/hip_runtime.h>
#include <hip/hip_fp16.h>

#define NEG_SLOPE 0.2f
#define ALPHA_FLAG 0.05f

typedef _Float16 h2t __attribute__((ext_vector_type(2)));
union h2u { unsigned u; h2t h; __half2 hh; float f; };
static __device__ __forceinline__ h2t u_as_h2(unsigned u) { h2u c; c.u = u; return c.h; }
static __device__ __forceinline__ float h2_as_f(__half2 h) { h2u c; c.hh = h; return c.f; }
static __device__ __forceinline__ h2t f_as_h2(float f) { h2u c; c.f = f; return c.h; }

static inline size_t align256(size_t x) { return (x + 255) & ~(size_t)255; }

// ---------- fused: prep (blocks [0,G)) + hist (blocks [G, G+NB_HIST)) ----------
// prep: c = relu(climber@W_c + b_c); gb = c@W_f + b_f   (independent of hist)
// hist: counts histogram + per-edge rank (atomicAdd return) for atomic-free scatter
__global__ __launch_bounds__(256) void prep_hist_kernel(
    const float* __restrict__ climber,
    const float* __restrict__ W_c, const float* __restrict__ b_c,
    const float* __restrict__ W_f1, const float* __restrict__ b_f1,
    const float* __restrict__ W_f2, const float* __restrict__ b_f2,
    float* __restrict__ gb1, float* __restrict__ gb2, int G,
    const int* __restrict__ dst, int E,
    int* __restrict__ counts, int* __restrict__ ranks) {
    __shared__ float c_sh[64];
    int t = threadIdx.x;
    if ((int)blockIdx.x < G) {
        int g = blockIdx.x;
        if (t < 64) {
            float acc = b_c[t];
#pragma unroll
            for (int k = 0; k < 4; ++k) acc = fmaf(climber[g * 4 + k], W_c[k * 64 + t], acc);
            c_sh[t] = fmaxf(acc, 0.f);
        }
        __syncthreads();
        if (t < 128) {
            float a1 = b_f1[t], a2 = b_f2[t];
#pragma unroll 8
            for (int h = 0; h < 64; ++h) {
                float cv = c_sh[h];
                a1 = fmaf(cv, W_f1[h * 128 + t], a1);
                a2 = fmaf(cv, W_f2[h * 128 + t], a2);
            }
            gb1[g * 128 + t] = a1;
            gb2[g * 128 + t] = a2;
        }
        return;
    }
    int i4 = ((blockIdx.x - G) * 256 + t) * 4;
    if (i4 + 3 < E) {
        int4 d = *(const int4*)&dst[i4];
        int4 r;
        r.x = atomicAdd(&counts[d.x], 1);
        r.y = atomicAdd(&counts[d.y], 1);
        r.z = atomicAdd(&counts[d.z], 1);
        r.w = atomicAdd(&counts[d.w], 1);
        *(int4*)&ranks[i4] = r;
    } else {
        for (int u = 0; u < 4; ++u)
            if (i4 + u < E) ranks[i4 + u] = atomicAdd(&counts[dst[i4 + u]], 1);
    }
}

// single-pass scan: block b computes its own prefix, then local chunk scan.
// Self-loop +1 per node folded in. Writes row_ptr only.
#define SCAN_CHUNK 1024
__global__ void scan_kernel(const int* __restrict__ counts, int* __restrict__ row_ptr, int N) {
    __shared__ int sh[256];
    int b = blockIdx.x, t = threadIdx.x;
    int pre = 0;
    for (int i0 = t * 4; i0 < b * SCAN_CHUNK; i0 += 1024) {
        int4 v = *(const int4*)&counts[i0];
        pre += v.x + v.y + v.z + v.w + 4;   // +1 self-loop each
    }
    sh[t] = pre;
    __syncthreads();
#pragma unroll
    for (int off = 128; off; off >>= 1) {
        if (t < off) sh[t] += sh[t + off];
        __syncthreads();
    }
    int base = sh[0];
    __syncthreads();
    int idx0 = b * SCAN_CHUNK + t * 4;
    int c[4];
    if (idx0 + 3 < N) {
        int4 v = *(const int4*)&counts[idx0];
        c[0] = v.x + 1; c[1] = v.y + 1; c[2] = v.z + 1; c[3] = v.w + 1;
    } else {
#pragma unroll
        for (int u = 0; u < 4; ++u) c[u] = (idx0 + u < N) ? counts[idx0 + u] + 1 : 0;
    }
    int s = c[0] + c[1] + c[2] + c[3];
    sh[t] = s;
    __syncthreads();
#pragma unroll
    for (int off = 1; off < 256; off <<= 1) {
        int add = (t >= off) ? sh[t - off] : 0;
        __syncthreads();
        sh[t] += add;
        __syncthreads();
    }
    int run = base + sh[t] - s;
#pragma unroll
    for (int u = 0; u < 4; ++u) {
        if (idx0 + u < N) {
            row_ptr[idx0 + u] = run;
            run += c[u];
            if (idx0 + u == N - 1) row_ptr[N] = run;
        }
    }
}

// ---------- xh body (shared by fused layer-1 kernel and standalone layer-2) ----------
// IN_MODE 1: compute x on the fly from x_all (input MLP + FiLM1)
// IN_MODE 0: load x (fp16) from xhalf
#define XH_NB 32
template <int IN_MODE>
static __device__ __forceinline__ void xh_body(
    int base, const __half* __restrict__ xhalf, const float* __restrict__ W_g,
    const float* __restrict__ a_src, const float* __restrict__ a_dst,
    __half* __restrict__ xh, float* __restrict__ s_src, float* __restrict__ s_dst,
    int N, const float* __restrict__ x_all, const int* __restrict__ batch,
    const float* __restrict__ W_in, const float* __restrict__ b_in,
    const float* __restrict__ gb1, float* __restrict__ x_sh, float* __restrict__ win_sh) {
    int t = threadIdx.x;
    if (IN_MODE) {
        for (int i = t; i < 448; i += 256)
            win_sh[i] = (i < 384) ? W_in[i] : b_in[i - 384];
        __syncthreads();
        int nd = t >> 3;            // node in tile: 0..31
        int jb = (t & 7) * 8;       // output channel block
        int n = base + nd;
        if (n < N) {
            float4 a = *(const float4*)&x_all[(size_t)n * 8];
            float2 b = *(const float2*)&x_all[(size_t)n * 8 + 4];
            float xa[6] = {a.x, a.y, a.z, a.w, b.x, b.y};
            int g = batch[n];
            const float* gbrow = &gb1[g * 128];
#pragma unroll
            for (int jj = 0; jj < 8; ++jj) {
                int j = jb + jj;
                float acc = win_sh[384 + j];
#pragma unroll
                for (int k = 0; k < 6; ++k) acc = fmaf(xa[k], win_sh[k * 64 + j], acc);
                x_sh[nd * 64 + j] = acc * (1.f + gbrow[j]) + gbrow[64 + j];
            }
        } else {
#pragma unroll
            for (int jj = 0; jj < 8; ++jj) x_sh[nd * 64 + jb + jj] = 0.f;
        }
    } else {
        int nvalid = N - base; if (nvalid > XH_NB) nvalid = XH_NB;
        int nhalves = nvalid * 64;   // multiple of 64; t*8 either fully in or out
        int idx = t * 8;
        uint4 raw = make_uint4(0, 0, 0, 0);
        if (idx < nhalves) raw = *(const uint4*)&xhalf[(size_t)base * 64 + idx];
        float2 f0 = __half22float2(*(__half2*)&raw.x);
        float2 f1 = __half22float2(*(__half2*)&raw.y);
        float2 f2 = __half22float2(*(__half2*)&raw.z);
        float2 f3 = __half22float2(*(__half2*)&raw.w);
        x_sh[idx + 0] = f0.x; x_sh[idx + 1] = f0.y;
        x_sh[idx + 2] = f1.x; x_sh[idx + 3] = f1.y;
        x_sh[idx + 4] = f2.x; x_sh[idx + 5] = f2.y;
        x_sh[idx + 6] = f3.x; x_sh[idx + 7] = f3.y;
    }
    __syncthreads();
    int c = t & 63;     // channel within head
    int g = t >> 6;     // wave id: handles nodes g*8..g*8+7, both heads
    float acc0[8], acc1[8];
#pragma unroll
    for (int i = 0; i < 8; ++i) { acc0[i] = 0.f; acc1[i] = 0.f; }
    const float* W0 = W_g + c;
    const float* W1 = W_g + 64 + c;
#pragma unroll 2
    for (int k = 0; k < 64; k += 4) {
        float w0[4], w1[4];
#pragma unroll
        for (int u = 0; u < 4; ++u) { w0[u] = W0[(k + u) * 128]; w1[u] = W1[(k + u) * 128]; }
#pragma unroll
        for (int i = 0; i < 8; ++i) {
            float4 xv = *(const float4*)&x_sh[(g * 8 + i) * 64 + k];
            acc0[i] = fmaf(xv.x, w0[0], acc0[i]);
            acc0[i] = fmaf(xv.y, w0[1], acc0[i]);
            acc0[i] = fmaf(xv.z, w0[2], acc0[i]);
            acc0[i] = fmaf(xv.w, w0[3], acc0[i]);
            acc1[i] = fmaf(xv.x, w1[0], acc1[i]);
            acc1[i] = fmaf(xv.y, w1[1], acc1[i]);
            acc1[i] = fmaf(xv.z, w1[2], acc1[i]);
            acc1[i] = fmaf(xv.w, w1[3], acc1[i]);
        }
    }
    float as0 = a_src[c], ad0 = a_dst[c];
    float as1 = a_src[64 + c], ad1 = a_dst[64 + c];
#pragma unroll
    for (int i = 0; i < 8; ++i) {
        int n = base + g * 8 + i;
        float ps0 = acc0[i] * as0, pd0 = acc0[i] * ad0;
        float ps1 = acc1[i] * as1, pd1 = acc1[i] * ad1;
#pragma unroll
        for (int off = 32; off; off >>= 1) {
            ps0 += __shfl_xor(ps0, off); pd0 += __shfl_xor(pd0, off);
            ps1 += __shfl_xor(ps1, off); pd1 += __shfl_xor(pd1, off);
        }
        if (n < N) {
            if (c == 0) {
                s_src[n * 2 + 0] = ps0; s_src[n * 2 + 1] = ps1;
                s_dst[n * 2 + 0] = pd0; s_dst[n * 2 + 1] = pd1;
            }
            __half2 hv = __floats2half2_rn(acc0[i], acc1[i]);
            *(__half2*)&xh[(size_t)n * 128 + c * 2] = hv;
        }
    }
}

// ---------- fused: scatter (blocks [0,NBS)) + layer-1 xh (blocks [NBS, ...)) ----------
// Independent: scatter reads ranks/counts/row_ptr -> csr_src; xh1 reads x_all/gb1 -> xh/scores.
__global__ __launch_bounds__(256) void scatter_xh1_kernel(
    const int* __restrict__ src, const int* __restrict__ dst,
    const int* __restrict__ ranks, const int* __restrict__ counts,
    const int* __restrict__ row_ptr, int Eh, int N, int NBS,
    int* __restrict__ csr_src,
    const float* __restrict__ W_g, const float* __restrict__ a_src,
    const float* __restrict__ a_dst, __half* __restrict__ xh,
    float* __restrict__ s_src, float* __restrict__ s_dst,
    const float* __restrict__ x_all, const int* __restrict__ batch,
    const float* __restrict__ W_in, const float* __restrict__ b_in,
    const float* __restrict__ gb1) {
    __shared__ float x_sh[XH_NB * 64];
    __shared__ float win_sh[6 * 64 + 64];
    if ((int)blockIdx.x < NBS) {
        int t = blockIdx.x * 256 + threadIdx.x;
        if (t < Eh) {
            int2 s2 = *(const int2*)&src[t * 2];
            int2 d2 = *(const int2*)&dst[t * 2];
            int2 r2 = *(const int2*)&ranks[t * 2];
            csr_src[row_ptr[d2.x] + r2.x] = s2.x;
            csr_src[row_ptr[d2.y] + r2.y] = s2.y;
        } else {
            int i = t - Eh;
            if (i < N) csr_src[row_ptr[i] + counts[i]] = i;   // self-loop (last slot)
        }
        return;
    }
    int base = (blockIdx.x - NBS) * XH_NB;
    xh_body<1>(base, nullptr, W_g, a_src, a_dst, xh, s_src, s_dst, N,
               x_all, batch, W_in, b_in, gb1, x_sh, win_sh);
}

// ---------- standalone layer-2 xh ----------
__global__ __launch_bounds__(256, 4) void xh2_kernel(
    const __half* __restrict__ xhalf, const float* __restrict__ W_g,
    const float* __restrict__ a_src, const float* __restrict__ a_dst,
    __half* __restrict__ xh, float* __restrict__ s_src, float* __restrict__ s_dst, int N) {
    __shared__ float x_sh[XH_NB * 64];
    __shared__ float win_sh[6 * 64 + 64];
    xh_body<0>(blockIdx.x * XH_NB, xhalf, W_g, a_src, a_dst, xh, s_src, s_dst, N,
               nullptr, nullptr, nullptr, nullptr, nullptr, x_sh, win_sh);
}

// dot2 helper: acc += w.h0*x.h0 + w.h1*x.h1 (fp32 accumulate)
static __device__ __forceinline__ float dot2acc(unsigned xbits, h2t w, float acc) {
#if __has_builtin(__builtin_amdgcn_fdot2)
    return __builtin_amdgcn_fdot2(u_as_h2(xbits), w, acc, false);
#else
    h2u cx; cx.u = xbits;
    float2 xf = __half22float2(cx.hh);
    h2u cw; cw.h = w;
    float2 wf = __half22float2(cw.hh);
    return fmaf(xf.x, wf.x, fmaf(xf.y, wf.y, acc));
#endif
}

// generic chunked single-node aggregation (any degree; used for rare deg>64)
static __device__ __forceinline__ void agg_one_slow(
    const char* __restrict__ xhb, const float* __restrict__ s_src,
    float2 sd, const int* __restrict__ csr_src, int beg, int end,
    int lane, int sub, unsigned q16, float2* __restrict__ ps_slot,
    float acc[4]) {
    float dp0 = 0.f, dp1 = 0.f;
    for (int chunk = beg; chunk < end; chunk += 64) {
        int m = end - chunk; if (m > 64) m = 64;
        if (lane < m) {
            int s = csr_src[chunk + lane];
            float2 ss = *(const float2*)&s_src[s * 2];
            float e0 = ss.x + sd.x, e1 = ss.y + sd.y;
            e0 = (e0 > 0.f) ? e0 : NEG_SLOPE * e0;
            e1 = (e1 > 0.f) ? e1 : NEG_SLOPE * e1;
            dp0 += __expf(e0); dp1 += __expf(e1);
        }
    }
#pragma unroll
    for (int off = 32; off; off >>= 1) {
        dp0 += __shfl_xor(dp0, off);
        dp1 += __shfl_xor(dp1, off);
    }
    float i0 = 0.5f / (dp0 + 1e-16f), i1 = 0.5f / (dp1 + 1e-16f);
    for (int chunk = beg; chunk < end; chunk += 64) {
        int m = end - chunk; if (m > 64) m = 64;
        float p0 = 0.f, p1 = 0.f; unsigned sb = 0;
        if (lane < m) {
            int s = csr_src[chunk + lane];
            sb = (unsigned)s << 8;
            float2 ss = *(const float2*)&s_src[s * 2];
            float e0 = ss.x + sd.x, e1 = ss.y + sd.y;
            e0 = (e0 > 0.f) ? e0 : NEG_SLOPE * e0;
            e1 = (e1 > 0.f) ? e1 : NEG_SLOPE * e1;
            p0 = __expf(e0); p1 = __expf(e1);
        }
        ps_slot[lane] = make_float2(h2_as_f(__floats2half2_rn(p0 * i0, p1 * i1)),
                                    __uint_as_float(sb));
        int mr = (m + 3) & ~3;
#pragma unroll 4
        for (int j = 0; j < mr; j += 4) {
            float2 ps = ps_slot[j + sub];
            h2t wpk = f_as_h2(ps.x);
            unsigned voff = __float_as_uint(ps.y) + q16;
            uint4 hv = *(const uint4*)(xhb + voff);
            acc[0] = dot2acc(hv.x, wpk, acc[0]);
            acc[1] = dot2acc(hv.y, wpk, acc[1]);
            acc[2] = dot2acc(hv.z, wpk, acc[2]);
            acc[3] = dot2acc(hv.w, wpk, acc[3]);
        }
    }
}

// ---------- wave-per-2-nodes aggregation (phase-interleaved dual pipeline) ----------
template <int MODE>
static __device__ __forceinline__ void agg_impl(
    const __half* __restrict__ xh, const float* __restrict__ s_src,
    const float* __restrict__ s_dst, const int* __restrict__ row_ptr,
    const int* __restrict__ csr_src, const float* __restrict__ b_g,
    const int* __restrict__ batch, const float* __restrict__ gb_film,
    __half* __restrict__ xout_h, int N, int half,
    const float* __restrict__ x_all,
    const float* __restrict__ W_cl1, const float* __restrict__ b_cl1,
    const float* __restrict__ W_cl2, const float* __restrict__ b_cl2,
    const float* __restrict__ W_fh1, const float* __restrict__ b_fh1,
    const float* __restrict__ W_fh2, const float* __restrict__ b_fh2,
    float* __restrict__ out) {
    __shared__ float2 ps_sh[4][2][64];   // (packed half2 alpha, row byte-offset)
    __shared__ float vh_sh[4][2][64];
    int lane = threadIdx.x & 63;
    int w = threadIdx.x >> 6;
    int n0 = (blockIdx.x * blockDim.x + threadIdx.x) >> 6;
    if (n0 >= half) return;
    int n1 = n0 + half;
    bool valid1 = n1 < N;
    const char* xhb = (const char*)xh;
    int sub = lane >> 4;
    unsigned q16 = (unsigned)(lane & 15) * 16u;
    float accA[4] = {0.f, 0.f, 0.f, 0.f};
    float accB[4] = {0.f, 0.f, 0.f, 0.f};

    int begA = row_ptr[n0], endA = row_ptr[n0 + 1];
    int begB = valid1 ? row_ptr[n1] : 0, endB = valid1 ? row_ptr[n1 + 1] : 0;
    int degA = endA - begA, degB = endB - begB;
    float2 sdA = *(const float2*)&s_dst[n0 * 2];
    float2 sdB = valid1 ? *(const float2*)&s_dst[n1 * 2] : make_float2(0.f, 0.f);

    if (degA <= 64 && degB <= 64) {
        int sA = (lane < degA) ? csr_src[begA + lane] : -1;
        int sB = (lane < degB) ? csr_src[begB + lane] : -1;
        float2 ssA = (sA >= 0) ? *(const float2*)&s_src[sA * 2] : make_float2(0.f, 0.f);
        float2 ssB = (sB >= 0) ? *(const float2*)&s_src[sB * 2] : make_float2(0.f, 0.f);
        float pA0 = 0.f, pA1 = 0.f, pB0 = 0.f, pB1 = 0.f;
        unsigned sbA = 0, sbB = 0;
        if (sA >= 0) {
            sbA = (unsigned)sA << 8;
            float e0 = ssA.x + sdA.x, e1 = ssA.y + sdA.y;
            e0 = (e0 > 0.f) ? e0 : NEG_SLOPE * e0;
            e1 = (e1 > 0.f) ? e1 : NEG_SLOPE * e1;
            pA0 = __expf(e0); pA1 = __expf(e1);
        }
        if (sB >= 0) {
            sbB = (unsigned)sB << 8;
            float e0 = ssB.x + sdB.x, e1 = ssB.y + sdB.y;
            e0 = (e0 > 0.f) ? e0 : NEG_SLOPE * e0;
            e1 = (e1 > 0.f) ? e1 : NEG_SLOPE * e1;
            pB0 = __expf(e0); pB1 = __expf(e1);
        }
        float dA0 = pA0, dA1 = pA1, dB0 = pB0, dB1 = pB1;
#pragma unroll
        for (int off = 32; off; off >>= 1) {
            dA0 += __shfl_xor(dA0, off); dA1 += __shfl_xor(dA1, off);
            dB0 += __shfl_xor(dB0, off); dB1 += __shfl_xor(dB1, off);
        }
        float iA0 = 0.5f / (dA0 + 1e-16f), iA1 = 0.5f / (dA1 + 1e-16f);
        float iB0 = 0.5f / (dB0 + 1e-16f), iB1 = 0.5f / (dB1 + 1e-16f);
        ps_sh[w][0][lane] = make_float2(h2_as_f(__floats2half2_rn(pA0 * iA0, pA1 * iA1)),
                                        __uint_as_float(sbA));
        ps_sh[w][1][lane] = make_float2(h2_as_f(__floats2half2_rn(pB0 * iB0, pB1 * iB1)),
                                        __uint_as_float(sbB));
        int mrA = (degA + 3) & ~3, mrB = (degB + 3) & ~3;
        int mr = mrA > mrB ? mrA : mrB;
#pragma unroll 2
        for (int j = 0; j < mr; j += 4) {
            float2 psA = ps_sh[w][0][j + sub];
            float2 psB = ps_sh[w][1][j + sub];
            unsigned voA = __float_as_uint(psA.y) + q16;
            unsigned voB = __float_as_uint(psB.y) + q16;
            uint4 hvA = *(const uint4*)(xhb + voA);
            uint4 hvB = *(const uint4*)(xhb + voB);
            h2t wA = f_as_h2(psA.x), wB = f_as_h2(psB.x);
            accA[0] = dot2acc(hvA.x, wA, accA[0]);
            accA[1] = dot2acc(hvA.y, wA, accA[1]);
            accA[2] = dot2acc(hvA.z, wA, accA[2]);
            accA[3] = dot2acc(hvA.w, wA, accA[3]);
            accB[0] = dot2acc(hvB.x, wB, accB[0]);
            accB[1] = dot2acc(hvB.y, wB, accB[1]);
            accB[2] = dot2acc(hvB.z, wB, accB[2]);
            accB[3] = dot2acc(hvB.w, wB, accB[3]);
        }
    } else {
        agg_one_slow(xhb, s_src, sdA, csr_src, begA, endA, lane, sub, q16,
                     &ps_sh[w][0][0], accA);
        if (valid1)
            agg_one_slow(xhb, s_src, sdB, csr_src, begB, endB, lane, sub, q16,
                         &ps_sh[w][1][0], accB);
    }
#pragma unroll
    for (int u = 0; u < 4; ++u) {
        accA[u] += __shfl_xor(accA[u], 16);
        accA[u] += __shfl_xor(accA[u], 32);
        accB[u] += __shfl_xor(accB[u], 16);
        accB[u] += __shfl_xor(accB[u], 32);
    }
    if (lane < 16) {
        *(float4*)&vh_sh[w][0][lane * 4] = make_float4(accA[0], accA[1], accA[2], accA[3]);
        *(float4*)&vh_sh[w][1][lane * 4] = make_float4(accB[0], accB[1], accB[2], accB[3]);
    }
    float bg = b_g[lane];
    float vA = fmaxf(vh_sh[w][0][lane] + bg, 0.f);
    float vB = fmaxf(vh_sh[w][1][lane] + bg, 0.f);
    if (MODE == 0) {
        int gA = batch[n0];
        vA = vA * (1.f + gb_film[gA * 128 + lane]) + gb_film[gA * 128 + 64 + lane];
        xout_h[(size_t)n0 * 64 + lane] = __float2half(vA);
        if (valid1) {
            int gB = batch[n1];
            vB = vB * (1.f + gb_film[gB * 128 + lane]) + gb_film[gB * 128 + 64 + lane];
            xout_h[(size_t)n1 * 64 + lane] = __float2half(vB);
        }
        return;
    }
    // ---- fused classifier + flag head, per node ----
    vh_sh[w][0][lane] = vA;
    vh_sh[w][1][lane] = vB;
    float4 w2 = *(const float4*)&W_cl2[lane * 4];
    float b1v = b_cl1[lane];
    for (int q = 0; q < 2; ++q) {
        int n = q ? n1 : n0;
        if (q && !valid1) break;
        float h = b1v;
#pragma unroll 4
        for (int k = 0; k < 64; k += 4) {
            float4 vq = *(const float4*)&vh_sh[w][q][k];   // uniform broadcast
            h = fmaf(vq.x, W_cl1[(k + 0) * 64 + lane], h);
            h = fmaf(vq.y, W_cl1[(k + 1) * 64 + lane], h);
            h = fmaf(vq.z, W_cl1[(k + 2) * 64 + lane], h);
            h = fmaf(vq.w, W_cl1[(k + 3) * 64 + lane], h);
        }
        h = fmaxf(h, 0.f);
        float o0 = h * w2.x, o1 = h * w2.y, o2 = h * w2.z, o3 = h * w2.w;
#pragma unroll
        for (int off = 32; off; off >>= 1) {
            o0 += __shfl_xor(o0, off); o1 += __shfl_xor(o1, off);
            o2 += __shfl_xor(o2, off); o3 += __shfl_xor(o3, off);
        }
        if (lane < 4) {
            float f0 = x_all[(size_t)n * 8 + 6], f1 = x_all[(size_t)n * 8 + 7];
            float lf = b_fh2[lane];
#pragma unroll
            for (int m = 0; m < 8; ++m) {
                float fm = fmaxf(fmaf(f0, W_fh1[m], fmaf(f1, W_fh1[8 + m], b_fh1[m])), 0.f);
                lf = fmaf(fm, W_fh2[m * 4 + lane], lf);
            }
            float om = (lane == 0) ? o0 : (lane == 1) ? o1 : (lane == 2) ? o2 : o3;
            out[(size_t)n * 4 + lane] = om + b_cl2[lane] + ALPHA_FLAG * lf;
        }
    }
}

__global__ __launch_bounds__(256) void agg_film_kernel(
    const __half* xh, const float* s_src, const float* s_dst, const int* row_ptr,
    const int* csr_src, const float* b_g, const int* batch, const float* gb_film,
    __half* xout_h, int N, int half) {
    agg_impl<0>(xh, s_src, s_dst, row_ptr, csr_src, b_g, batch, gb_film, xout_h, N, half,
                nullptr, nullptr, nullptr, nullptr, nullptr, nullptr, nullptr,
                nullptr, nullptr, nullptr);
}

__global__ __launch_bounds__(256) void agg_cls_kernel(
    const __half* xh, const float* s_src, const float* s_dst, const int* row_ptr,
    const int* csr_src, const float* b_g, int N, int half, const float* x_all,
    const float* W_cl1, const float* b_cl1, const float* W_cl2, const float* b_cl2,
    const float* W_fh1, const float* b_fh1, const float* W_fh2, const float* b_fh2,
    float* out) {
    agg_impl<1>(xh, s_src, s_dst, row_ptr, csr_src, b_g, nullptr, nullptr, nullptr, N, half,
                x_all, W_cl1, b_cl1, W_cl2, b_cl2, W_fh1, b_fh1, W_fh2, b_fh2, out);
}

extern "C" void kernel_launch(void* const* d_in, const int* in_sizes, int n_in,
                              void* d_out, int out_size, void* d_ws, size_t ws_size,
                              hipStream_t stream) {
    const float* x_all   = (const float*)d_in[0];
    const float* climber = (const float*)d_in[1];
    const int*   eidx    = (const int*)d_in[2];
    const int*   batch   = (const int*)d_in[3];
    const float* W_in  = (const float*)d_in[4];
    const float* b_in  = (const float*)d_in[5];
    const float* W_c   = (const float*)d_in[6];
    const float* b_c   = (const float*)d_in[7];
    const float* W_f1  = (const float*)d_in[8];
    const float* b_f1  = (const float*)d_in[9];
    const float* W_f2  = (const float*)d_in[10];
    const float* b_f2  = (const float*)d_in[11];
    const float* W_g1  = (const float*)d_in[12];
    const float* a_s1  = (const float*)d_in[13];
    const float* a_d1  = (const float*)d_in[14];
    const float* b_g1  = (const float*)d_in[15];
    const float* W_g2  = (const float*)d_in[16];
    const float* a_s2  = (const float*)d_in[17];
    const float* a_d2  = (const float*)d_in[18];
    const float* b_g2  = (const float*)d_in[19];
    const float* W_cl1 = (const float*)d_in[20];
    const float* b_cl1 = (const float*)d_in[21];
    const float* W_cl2 = (const float*)d_in[22];
    const float* b_cl2 = (const float*)d_in[23];
    const float* W_fh1 = (const float*)d_in[24];
    const float* b_fh1 = (const float*)d_in[25];
    const float* W_fh2 = (const float*)d_in[26];
    const float* b_fh2 = (const float*)d_in[27];
    float* out = (float*)d_out;

    const int N = in_sizes[0] / 8;      // 50000
    const int E = in_sizes[2] / 2;      // 800000 (even)
    const int G = in_sizes[1] / 4;      // 128
    const int* src = eidx;
    const int* dst = eidx + E;
    const int NB_SCAN = (N + SCAN_CHUNK - 1) / SCAN_CHUNK;   // 49
    const int NB_HIST = (E / 4 + 255) / 256;                 // 782
    const int NB_SCAT = (E / 2 + N + 255) / 256;             // 1759
    const int NB_XH   = (N + XH_NB - 1) / XH_NB;             // 1563
    const int half = (N + 1) / 2;       // 25000

    char* ws = (char*)d_ws;
    size_t off = 0;
    auto alloc = [&](size_t bytes) { char* p = ws + off; off += align256(bytes); return p; };
    float*  gb1     = (float*)alloc((size_t)G * 128 * 4);
    float*  gb2     = (float*)alloc((size_t)G * 128 * 4);
    __half* xbuf    = (__half*)alloc((size_t)N * 64 * 2);
    __half* xh      = (__half*)alloc((size_t)N * 128 * 2);
    float*  s_src   = (float*)alloc((size_t)N * 2 * 4);
    float*  s_dst   = (float*)alloc((size_t)N * 2 * 4);
    int*    counts  = (int*)alloc((size_t)N * 4);
    int*    ranks   = (int*)alloc((size_t)E * 4);
    int*    row_ptr = (int*)alloc((size_t)(N + 1) * 4);
    int*    csr_src = (int*)alloc((size_t)(E + N) * 4);
    (void)ws_size;

    // 1. prep (FiLM params) + hist, fused (independent work, one dispatch)
    hipMemsetAsync(counts, 0, (size_t)N * 4, stream);
    prep_hist_kernel<<<G + NB_HIST, 256, 0, stream>>>(climber, W_c, b_c, W_f1, b_f1,
                                                      W_f2, b_f2, gb1, gb2, G,
                                                      dst, E, counts, ranks);
    // 2. scan
    scan_kernel<<<NB_SCAN, 256, 0, stream>>>(counts, row_ptr, N);
    // 3. scatter + layer-1 xh (input MLP + FiLM1 + W_g1 + scores), fused
    scatter_xh1_kernel<<<NB_SCAT + NB_XH, 256, 0, stream>>>(src, dst, ranks, counts, row_ptr,
                                                            E / 2, N, NB_SCAT, csr_src,
                                                            W_g1, a_s1, a_d1, xh, s_src, s_dst,
                                                            x_all, batch, W_in, b_in, gb1);
    // 4. layer-1 aggregation (+FiLM2 -> fp16 xbuf)
    agg_film_kernel<<<(half * 64 + 255) / 256, 256, 0, stream>>>(xh, s_src, s_dst, row_ptr,
                                                                 csr_src, b_g1, batch, gb2,
                                                                 xbuf, N, half);
    // 5. layer-2 xh
    xh2_kernel<<<NB_XH, 256, 0, stream>>>(xbuf, W_g2, a_s2, a_d2, xh, s_src, s_dst, N);
    // 6. layer-2 aggregation + classifier + flag head
    agg_cls_kernel<<<(half * 64 + 255) / 256, 256, 0, stream>>>(xh, s_src, s_dst, row_ptr,
                                                                csr_src, b_g2, N, half, x_all,
                                                                W_cl1, b_cl1, W_cl2, b_cl2,
                                                                W_fh1, b_fh1, W_fh2, b_fh2, out);
}